// Round 1
// baseline (10503.001 us; speedup 1.0000x reference)
//
#include <hip/hip_runtime.h>
#include <hip/hip_bf16.h>
#include <math.h>

// RSWABlock: x:(16,192,128,128) fp32 -> pre1(1x1) -> dw3x3 -> LN(ch) ->
// 8x8 windows -> (attention * gMLP) -> merge -> proj(1x1) -> + x
// Round 3: attention + gMLP moved to bf16 MFMA (16x16x32), weights
// pre-transposed to bf16 [n][k] in workspace by k_prep.

#define DIM    192
#define IMG_H  128
#define IMG_W  128
#define HW     16384        // 128*128
#define NB     16           // batch
#define NWIN   4096         // 16 batches * 16 * 16 windows
#define NHEADS 6
#define HDIM   32
#define ATT_SCALE 0.17677669529663687f  // 32^-0.5
#define LN_EPS 1e-6f

typedef __hip_bfloat16 bf16;
__device__ __forceinline__ float b2f(bf16 v) { return __bfloat162float(v); }
__device__ __forceinline__ bf16  f2b(float v) { return __float2bfloat16(v); }

typedef __bf16 bh8 __attribute__((ext_vector_type(8)));
typedef float  f32x4 __attribute__((ext_vector_type(4)));
#define MFMA16(a, b, c) __builtin_amdgcn_mfma_f32_16x16x32_bf16((a), (b), (c), 0, 0, 0)

// ---------------------------------------------------------------------------
// K0: weight prep — dst[n*K + k] = bf16(src[k*N + n])   (transpose + cast)
// grid (N/32, K/32), block 256.
// ---------------------------------------------------------------------------
__global__ __launch_bounds__(256) void k_prep(
    const float* __restrict__ src, bf16* __restrict__ dst, int K, int N)
{
    __shared__ float t[32][33];
    const int tid = threadIdx.x;
    const int lx = tid & 31, ly = tid >> 5;
    const int n0 = blockIdx.x * 32, k0 = blockIdx.y * 32;
    for (int r = ly; r < 32; r += 8)
        t[r][lx] = src[(size_t)(k0 + r) * N + n0 + lx];
    __syncthreads();
    for (int r = ly; r < 32; r += 8)
        dst[(size_t)(n0 + r) * K + k0 + lx] = f2b(t[lx][r]);
}

// ---------------------------------------------------------------------------
// K1: h1[b,o,hw] = sum_c x[b,c,hw] * w_pre1[o,c] + b_pre1[o]   (all fp32)
// grid (1024, 3): blockIdx.x = 256-pixel tile, blockIdx.y = 64-o tile
// ---------------------------------------------------------------------------
__global__ __launch_bounds__(256) void k_pre1(
    const float* __restrict__ x, const float* __restrict__ w,
    const float* __restrict__ bias, float* __restrict__ h1)
{
    __shared__ __align__(16) float lw[64 * 192];   // 48 KB [o][c]
    const int tid = threadIdx.x;
    const int obase = blockIdx.y * 64;
    for (int i = tid; i < 64 * 192; i += 256)
        lw[i] = w[obase * 192 + i];
    __syncthreads();

    const int g  = blockIdx.x * 256 + tid;      // global pixel in [0, NB*HW)
    const int b  = g >> 14;
    const int hw = g & (HW - 1);
    const float* xb = x + (size_t)b * DIM * HW + hw;

    float acc[64];
#pragma unroll
    for (int o = 0; o < 64; ++o) acc[o] = bias[obase + o];

    for (int c = 0; c < DIM; c += 4) {
        float xv0 = xb[(size_t)(c + 0) * HW];
        float xv1 = xb[(size_t)(c + 1) * HW];
        float xv2 = xb[(size_t)(c + 2) * HW];
        float xv3 = xb[(size_t)(c + 3) * HW];
#pragma unroll
        for (int o = 0; o < 64; ++o) {
            const float4 wv = *(const float4*)&lw[o * 192 + c];
            acc[o] += wv.x * xv0 + wv.y * xv1 + wv.z * xv2 + wv.w * xv3;
        }
    }
    float* hb = h1 + (size_t)b * DIM * HW + hw;
#pragma unroll
    for (int o = 0; o < 64; ++o) hb[(size_t)(obase + o) * HW] = acc[o];
}

// ---------------------------------------------------------------------------
// K2: depthwise 3x3 (SAME) + bias, LayerNorm over channels, window partition.
// One block per window. Writes p[win, t, c] bf16.
// ---------------------------------------------------------------------------
__global__ __launch_bounds__(256) void k_dwln(
    const float* __restrict__ h1, const float* __restrict__ w_dw,
    const float* __restrict__ b_dw, const float* __restrict__ ln_g,
    const float* __restrict__ ln_b, bf16* __restrict__ p)
{
    __shared__ float tile[64 * 192];      // [pix][ch] post-conv, 48 KB
    __shared__ float patch[32 * 101];     // [ch][10x10 + pad], 12.9 KB
    const int tid = threadIdx.x;
    const int win = blockIdx.x;
    const int b = win >> 8, rem = win & 255;
    const int r0 = (rem >> 4) * 8, c0 = (rem & 15) * 8;

    for (int cc = 0; cc < 6; ++cc) {      // 6 chunks of 32 channels
        for (int i = tid; i < 3200; i += 256) {
            int ch = i / 100, pp = i % 100;
            int pr = pp / 10, pc = pp % 10;
            int gy = r0 - 1 + pr, gx = c0 - 1 + pc;
            float v = 0.f;
            if ((unsigned)gy < 128u && (unsigned)gx < 128u)
                v = h1[(((size_t)b * DIM + cc * 32 + ch) * IMG_H + gy) * IMG_W + gx];
            patch[ch * 101 + pp] = v;
        }
        __syncthreads();
        for (int i = tid; i < 2048; i += 256) {     // 64 pix * 32 ch
            int pix = i >> 5, chl = i & 31;
            int ch = cc * 32 + chl;
            int r = pix >> 3, c = pix & 7;
            float acc = b_dw[ch];
#pragma unroll
            for (int ky = 0; ky < 3; ++ky)
#pragma unroll
                for (int kx = 0; kx < 3; ++kx)
                    acc = fmaf(w_dw[ch * 9 + ky * 3 + kx],
                               patch[chl * 101 + (r + ky) * 10 + (c + kx)], acc);
            tile[pix * 192 + ch] = acc;
        }
        __syncthreads();
    }
    // LayerNorm per pixel over 192 channels: 4 threads per pixel
    const int pix = tid >> 2, sub = tid & 3;
    float s1 = 0.f, s2 = 0.f;
    for (int j = 0; j < 48; ++j) {
        float v = tile[pix * 192 + sub * 48 + j];
        s1 += v; s2 += v * v;
    }
    s1 += __shfl_xor(s1, 1); s2 += __shfl_xor(s2, 1);
    s1 += __shfl_xor(s1, 2); s2 += __shfl_xor(s2, 2);
    float mu  = s1 * (1.f / 192.f);
    float var = fmaxf(s2 * (1.f / 192.f) - mu * mu, 0.f);
    float rstd = rsqrtf(var + LN_EPS);
    bf16* pout = p + ((size_t)win * 64 + pix) * 192 + sub * 48;
    for (int j = 0; j < 48; ++j) {
        int c = sub * 48 + j;
        pout[j] = f2b((tile[pix * 192 + c] - mu) * rstd * ln_g[c] + ln_b[c]);
    }
}

// ---------------------------------------------------------------------------
// K3: per-window QKV + attention, all matmuls via bf16 MFMA 16x16x32.
// One block (256 thr = 4 waves) per window.
// LDS: qs[64][200], ks[64][200], vT[192][72], ps[64][200], wt[96][200]
//      ss fp32[64][66] overlaps ps, pb bf16[64][72] overlaps wt.
// ---------------------------------------------------------------------------
__global__ __launch_bounds__(256) void k_attn(
    const bf16* __restrict__ p, const bf16* __restrict__ wqkvt,
    const float* __restrict__ b_qkv, bf16* __restrict__ a)
{
    __shared__ __align__(16) char smem[142848];
    bf16*  qs = (bf16*)(smem);             // [64][200] 25600 B
    bf16*  ks = (bf16*)(smem + 25600);     // [64][200] 25600 B
    bf16*  vT = (bf16*)(smem + 51200);     // [192][72] 27648 B
    bf16*  ps = (bf16*)(smem + 78848);     // [64][200] 25600 B
    bf16*  wt = (bf16*)(smem + 104448);    // [96][200] 38400 B
    float* ss = (float*)(smem + 78848);    // [64][66] fp32, overlaps ps (dead)
    bf16*  pb = (bf16*)(smem + 104448);    // [64][72], overlaps wt (dead)

    const int tid  = threadIdx.x;
    const int wave = tid >> 6, lane = tid & 63;
    const int lid  = lane & 15, lhi = lane >> 4;
    const int win  = blockIdx.x;
    const f32x4 zero4 = {0.f, 0.f, 0.f, 0.f};

    // stage p window (64 x 192) into padded LDS
    const bf16* pwin = p + (size_t)win * 64 * 192;
    for (int i = tid; i < 1536; i += 256) {
        int r = i / 24, c = (i % 24) * 8;
        *(bh8*)(ps + r * 200 + c) = *(const bh8*)(pwin + r * 192 + c);
    }

    // ---- QKV: (64 x 192) @ (192 x 576), weight pre-transposed [576][192] ----
    const int mb  = (wave >> 1) * 32;   // wave m-tile base (rows)
    const int nbw = (wave & 1) * 48;    // wave n-tile base within 96-col chunk
    for (int nc = 0; nc < 6; ++nc) {    // 6 chunks of 96 output cols
        for (int i = tid; i < 2304; i += 256) {   // stage weight chunk 96x192
            int r = i / 24, c = (i % 24) * 8;
            *(bh8*)(wt + r * 200 + c) =
                *(const bh8*)(wqkvt + (size_t)(nc * 96 + r) * 192 + c);
        }
        __syncthreads();

        f32x4 acc[2][3];
#pragma unroll
        for (int mi = 0; mi < 2; ++mi)
#pragma unroll
            for (int ni = 0; ni < 3; ++ni) {
                float b = b_qkv[nc * 96 + nbw + ni * 16 + lid];
                f32x4 bb = {b, b, b, b};
                acc[mi][ni] = bb;
            }
#pragma unroll
        for (int k8 = 0; k8 < 6; ++k8) {
            bh8 af[2], bfr[3];
#pragma unroll
            for (int mi = 0; mi < 2; ++mi)
                af[mi] = *(const bh8*)(ps + (mb + mi * 16 + lid) * 200 + k8 * 32 + 8 * lhi);
#pragma unroll
            for (int ni = 0; ni < 3; ++ni)
                bfr[ni] = *(const bh8*)(wt + (nbw + ni * 16 + lid) * 200 + k8 * 32 + 8 * lhi);
#pragma unroll
            for (int mi = 0; mi < 2; ++mi)
#pragma unroll
                for (int ni = 0; ni < 3; ++ni)
                    acc[mi][ni] = MFMA16(af[mi], bfr[ni], acc[mi][ni]);
        }
        // writeback: D lane holds col = lid, rows = 4*lhi + reg (within m-tile)
#pragma unroll
        for (int mi = 0; mi < 2; ++mi)
#pragma unroll
            for (int ni = 0; ni < 3; ++ni) {
                const int colg = nc * 96 + nbw + ni * 16 + lid;
#pragma unroll
                for (int r = 0; r < 4; ++r) {
                    const int t = mb + mi * 16 + 4 * lhi + r;
                    float v = acc[mi][ni][r];
                    if (colg < 192)       qs[t * 200 + colg] = f2b(v * ATT_SCALE);
                    else if (colg < 384)  ks[t * 200 + (colg - 192)] = f2b(v);
                    else                  vT[(colg - 384) * 72 + t] = f2b(v);
                }
            }
        __syncthreads();
    }

    // ---- per-head attention ----
    for (int h = 0; h < NHEADS; ++h) {
        // S = Q K^T  (scale folded into Q); wave handles 16-row tile
        bh8 qf = *(const bh8*)(qs + (wave * 16 + lid) * 200 + h * 32 + 8 * lhi);
        f32x4 sacc[4];
#pragma unroll
        for (int ni = 0; ni < 4; ++ni) {
            bh8 kf = *(const bh8*)(ks + (ni * 16 + lid) * 200 + h * 32 + 8 * lhi);
            sacc[ni] = MFMA16(qf, kf, zero4);
        }
#pragma unroll
        for (int ni = 0; ni < 4; ++ni)
#pragma unroll
            for (int r = 0; r < 4; ++r)
                ss[(wave * 16 + 4 * lhi + r) * 66 + ni * 16 + lid] = sacc[ni][r];
        __syncthreads();

        // softmax rows: 4 threads / row, write P as bf16
        {
            const int t = tid >> 2, sub = tid & 3;
            float e[16];
            float mx = -1e30f;
#pragma unroll
            for (int j = 0; j < 16; ++j) mx = fmaxf(mx, ss[t * 66 + sub * 16 + j]);
            mx = fmaxf(mx, __shfl_xor(mx, 1));
            mx = fmaxf(mx, __shfl_xor(mx, 2));
            float sum = 0.f;
#pragma unroll
            for (int j = 0; j < 16; ++j) {
                e[j] = __expf(ss[t * 66 + sub * 16 + j] - mx);
                sum += e[j];
            }
            sum += __shfl_xor(sum, 1);
            sum += __shfl_xor(sum, 2);
            float inv = 1.f / sum;
#pragma unroll
            for (int j = 0; j < 16; ++j)
                pb[t * 72 + sub * 16 + j] = f2b(e[j] * inv);
        }
        __syncthreads();

        // O = P V  (V stored transposed [ch][tok])
#pragma unroll
        for (int nb2 = 0; nb2 < 2; ++nb2) {
            f32x4 oacc = zero4;
#pragma unroll
            for (int kk = 0; kk < 2; ++kk) {
                bh8 pf = *(const bh8*)(pb + (wave * 16 + lid) * 72 + kk * 32 + 8 * lhi);
                bh8 vf = *(const bh8*)(vT + (h * 32 + nb2 * 16 + lid) * 72 + kk * 32 + 8 * lhi);
                oacc = MFMA16(pf, vf, oacc);
            }
#pragma unroll
            for (int r = 0; r < 4; ++r) {
                const int t = wave * 16 + 4 * lhi + r;
                a[((size_t)win * 64 + t) * 192 + h * 32 + nb2 * 16 + lid] = f2b(oacc[r]);
            }
        }
        __syncthreads();
    }
}

// ---------------------------------------------------------------------------
// K4: gMLP (gelu(p@w1+b1)@w2+b2) via MFMA, multiply with attn out in-place.
// One block (4 waves) per window; 12 hidden-chunks of 64.
// ---------------------------------------------------------------------------
__global__ __launch_bounds__(256) void k_gmlp(
    const bf16* __restrict__ p, const bf16* __restrict__ w1t,
    const float* __restrict__ b1, const bf16* __restrict__ w2t,
    const float* __restrict__ b2, bf16* __restrict__ a)
{
    __shared__ __align__(16) char smem[88064];
    bf16* ps  = (bf16*)(smem);             // [64][200] 25600 B
    bf16* w1c = (bf16*)(smem + 25600);     // [64][200] 25600 B
    bf16* w2c = (bf16*)(smem + 51200);     // [192][72] 27648 B
    bf16* hb  = (bf16*)(smem + 78848);     // [64][72]   9216 B

    const int tid  = threadIdx.x;
    const int wave = tid >> 6, lane = tid & 63;
    const int lid  = lane & 15, lhi = lane >> 4;
    const int win  = blockIdx.x;

    const bf16* pwin = p + (size_t)win * 64 * 192;
    for (int i = tid; i < 1536; i += 256) {
        int r = i / 24, c = (i % 24) * 8;
        *(bh8*)(ps + r * 200 + c) = *(const bh8*)(pwin + r * 192 + c);
    }

    f32x4 acc2[12];
#pragma unroll
    for (int ni = 0; ni < 12; ++ni) {
        float b = b2[ni * 16 + lid];
        f32x4 bb = {b, b, b, b};
        acc2[ni] = bb;
    }
    const int mb = (wave >> 1) * 32, nb = (wave & 1) * 32;

    for (int hc = 0; hc < 12; ++hc) {
        for (int i = tid; i < 1536; i += 256) {   // w1 chunk [64 hid][192 k]
            int r = i / 24, c = (i % 24) * 8;
            *(bh8*)(w1c + r * 200 + c) =
                *(const bh8*)(w1t + (size_t)(hc * 64 + r) * 192 + c);
        }
        for (int i = tid; i < 1536; i += 256) {   // w2 chunk [192 out][64 k]
            int r = i / 8, c = (i % 8) * 8;
            *(bh8*)(w2c + r * 72 + c) =
                *(const bh8*)(w2t + (size_t)r * 768 + hc * 64 + c);
        }
        __syncthreads();

        // GEMM1: hidden chunk (64 x 64), wave tile 32 x 32
        f32x4 acc1[2][2];
#pragma unroll
        for (int mi = 0; mi < 2; ++mi)
#pragma unroll
            for (int ni = 0; ni < 2; ++ni) {
                float b = b1[hc * 64 + nb + ni * 16 + lid];
                f32x4 bb = {b, b, b, b};
                acc1[mi][ni] = bb;
            }
#pragma unroll
        for (int k8 = 0; k8 < 6; ++k8) {
            bh8 af0 = *(const bh8*)(ps + (mb + lid) * 200 + k8 * 32 + 8 * lhi);
            bh8 af1 = *(const bh8*)(ps + (mb + 16 + lid) * 200 + k8 * 32 + 8 * lhi);
            bh8 bf0 = *(const bh8*)(w1c + (nb + lid) * 200 + k8 * 32 + 8 * lhi);
            bh8 bf1 = *(const bh8*)(w1c + (nb + 16 + lid) * 200 + k8 * 32 + 8 * lhi);
            acc1[0][0] = MFMA16(af0, bf0, acc1[0][0]);
            acc1[0][1] = MFMA16(af0, bf1, acc1[0][1]);
            acc1[1][0] = MFMA16(af1, bf0, acc1[1][0]);
            acc1[1][1] = MFMA16(af1, bf1, acc1[1][1]);
        }
        // exact GELU -> hb (bf16)
#pragma unroll
        for (int mi = 0; mi < 2; ++mi)
#pragma unroll
            for (int ni = 0; ni < 2; ++ni)
#pragma unroll
                for (int r = 0; r < 4; ++r) {
                    int row = mb + mi * 16 + 4 * lhi + r;
                    int col = nb + ni * 16 + lid;
                    float xv = acc1[mi][ni][r];
                    hb[row * 72 + col] =
                        f2b(0.5f * xv * (1.f + erff(xv * 0.70710678118654752f)));
                }
        __syncthreads();

        // GEMM2: acc2 (16 rows x 192 cols per wave) += hb @ w2chunk
#pragma unroll
        for (int kk = 0; kk < 2; ++kk) {
            bh8 hf = *(const bh8*)(hb + (wave * 16 + lid) * 72 + kk * 32 + 8 * lhi);
#pragma unroll
            for (int ni = 0; ni < 12; ++ni) {
                bh8 wf = *(const bh8*)(w2c + (ni * 16 + lid) * 72 + kk * 32 + 8 * lhi);
                acc2[ni] = MFMA16(hf, wf, acc2[ni]);
            }
        }
        __syncthreads();
    }

    // epilogue: out = attn * gmlp, in-place on a
    bf16* awin = a + (size_t)win * 64 * 192;
#pragma unroll
    for (int ni = 0; ni < 12; ++ni)
#pragma unroll
        for (int r = 0; r < 4; ++r) {
            int t = wave * 16 + 4 * lhi + r;
            int col = ni * 16 + lid;
            size_t idx = (size_t)t * 192 + col;
            awin[idx] = f2b(acc2[ni][r] * b2f(awin[idx]));
        }
}

// ---------------------------------------------------------------------------
// K5: proj 1x1 + bias + residual, store NCHW fp32 to d_out.
// One block per half-window (32 tokens). grid 8192.
// ---------------------------------------------------------------------------
__global__ __launch_bounds__(256) void k_proj(
    const bf16* __restrict__ m, const float* __restrict__ w_proj,
    const float* __restrict__ b_proj, const float* __restrict__ x,
    float* __restrict__ out)
{
    __shared__ float mw[32 * 194];    // tokens, padded
    __shared__ float ot[32 * 193];    // [pix][o] result, padded
    const int tid = threadIdx.x;
    const int win = blockIdx.x >> 1;
    const int thalf = (blockIdx.x & 1) * 32;
    const int b = win >> 8, rem = win & 255;
    const int r0 = (rem >> 4) * 8, c0 = (rem & 15) * 8;
    const bf16* mwin = m + ((size_t)win * 64 + thalf) * 192;
    for (int i = tid; i < 6144; i += 256) {
        int tt = i / 192, c = i % 192;
        mw[tt * 194 + c] = b2f(mwin[i]);
    }
    const int lt = tid >> 3, obase = (tid & 7) * 24;
    float acc[24];
#pragma unroll
    for (int oo = 0; oo < 24; ++oo) acc[oo] = b_proj[obase + oo];
    __syncthreads();

    for (int c = 0; c < 192; ++c) {
        float mv = mw[lt * 194 + c];
#pragma unroll
        for (int oo = 0; oo < 24; ++oo)
            acc[oo] = fmaf(mv, w_proj[(size_t)(obase + oo) * 192 + c], acc[oo]);
    }
#pragma unroll
    for (int oo = 0; oo < 24; ++oo) ot[lt * 193 + obase + oo] = acc[oo];
    __syncthreads();

    for (int i = tid; i < 6144; i += 256) {
        int o = i >> 5, pix = i & 31;       // 192 o x 32 pix
        int t = thalf + pix;
        size_t idx = (((size_t)b * DIM + o) * IMG_H + r0 + (t >> 3)) * IMG_W
                     + c0 + (t & 7);
        out[idx] = ot[pix * 193 + o] + x[idx];   // + residual
    }
}

// ---------------------------------------------------------------------------
extern "C" void kernel_launch(void* const* d_in, const int* in_sizes, int n_in,
                              void* d_out, int out_size, void* d_ws, size_t ws_size,
                              hipStream_t stream)
{
    const float* x      = (const float*)d_in[0];
    const float* w_pre1 = (const float*)d_in[1];
    const float* b_pre1 = (const float*)d_in[2];
    const float* w_dw   = (const float*)d_in[3];
    const float* b_dw   = (const float*)d_in[4];
    const float* ln_g   = (const float*)d_in[5];
    const float* ln_b   = (const float*)d_in[6];
    const float* w_qkv  = (const float*)d_in[7];
    const float* b_qkv  = (const float*)d_in[8];
    const float* w1     = (const float*)d_in[9];
    const float* b1     = (const float*)d_in[10];
    const float* w2     = (const float*)d_in[11];
    const float* b2     = (const float*)d_in[12];
    const float* w_proj = (const float*)d_in[13];
    const float* b_proj = (const float*)d_in[14];
    float* out = (float*)d_out;

    const size_t NELEM = (size_t)NB * DIM * HW;   // 50,331,648
    // h1 lives fp32 inside d_out (dead before k_proj overwrites d_out)
    float* h1 = (float*)d_out;
    bf16* p = (bf16*)d_ws;           // LN'd window tokens (win, t, c)
    bf16* a = p + NELEM;             // attn out, then attn*gmlp (in-place)
    bf16* wqkvt = a + NELEM;         // [576][192] transposed bf16 weights
    bf16* w1t   = wqkvt + 3 * DIM * DIM;   // [768][192]
    bf16* w2t   = w1t + 4 * DIM * DIM;     // [192][768]

    // weight prep (transpose + cast); independent of data path
    k_prep<<<dim3(18, 6),  256, 0, stream>>>(w_qkv, wqkvt, DIM, 3 * DIM);
    k_prep<<<dim3(24, 6),  256, 0, stream>>>(w1, w1t, DIM, 4 * DIM);
    k_prep<<<dim3(6, 24),  256, 0, stream>>>(w2, w2t, 4 * DIM, DIM);

    k_pre1<<<dim3(1024, 3), 256, 0, stream>>>(x, w_pre1, b_pre1, h1);
    k_dwln<<<dim3(NWIN), 256, 0, stream>>>(h1, w_dw, b_dw, ln_g, ln_b, p);
    k_attn<<<dim3(NWIN), 256, 0, stream>>>(p, wqkvt, b_qkv, a);
    k_gmlp<<<dim3(NWIN), 256, 0, stream>>>(p, w1t, b1, w2t, b2, a);
    k_proj<<<dim3(NWIN * 2), 256, 0, stream>>>(a, w_proj, b_proj, x, out);
}

// Round 4
// 2723.768 us; speedup vs baseline: 3.8561x; 3.8561x over previous
//
#include <hip/hip_runtime.h>
#include <hip/hip_bf16.h>
#include <math.h>

// RSWABlock: x:(16,192,128,128) fp32 -> pre1(1x1) -> dw3x3 -> LN(ch) ->
// 8x8 windows -> (attention * gMLP) -> merge -> proj(1x1) -> + x
// Round 6: same as round 5 (k_proj as bf16 MFMA GEMM, w_proj cast in-kernel)
// with the grid bug fixed: k_proj handles 2 windows/block -> grid NWIN/2
// (=2048), NOT NWIN*2 (=8192, which drove batch index b to 63 -> OOB fault).

#define DIM    192
#define IMG_H  128
#define IMG_W  128
#define HW     16384        // 128*128
#define NB     16           // batch
#define NWIN   4096         // 16 batches * 16 * 16 windows
#define NHEADS 6
#define HDIM   32
#define ATT_SCALE 0.17677669529663687f  // 32^-0.5
#define LN_EPS 1e-6f

typedef __hip_bfloat16 bf16;
__device__ __forceinline__ float b2f(bf16 v) { return __bfloat162float(v); }
__device__ __forceinline__ bf16  f2b(float v) { return __float2bfloat16(v); }

typedef __bf16 bh8 __attribute__((ext_vector_type(8)));
typedef float  f32x4 __attribute__((ext_vector_type(4)));
#define MFMA16(a, b, c) __builtin_amdgcn_mfma_f32_16x16x32_bf16((a), (b), (c), 0, 0, 0)

// ---------------------------------------------------------------------------
// K0: weight prep — dst[n*K + k] = bf16(src[k*N + n])   (transpose + cast)
// grid (N/32, K/32), block 256.
// ---------------------------------------------------------------------------
__global__ __launch_bounds__(256) void k_prep(
    const float* __restrict__ src, bf16* __restrict__ dst, int K, int N)
{
    __shared__ float t[32][33];
    const int tid = threadIdx.x;
    const int lx = tid & 31, ly = tid >> 5;
    const int n0 = blockIdx.x * 32, k0 = blockIdx.y * 32;
    for (int r = ly; r < 32; r += 8)
        t[r][lx] = src[(size_t)(k0 + r) * N + n0 + lx];
    __syncthreads();
    for (int r = ly; r < 32; r += 8)
        dst[(size_t)(n0 + r) * K + k0 + lx] = f2b(t[lx][r]);
}

// ---------------------------------------------------------------------------
// K1: h1[b,o,hw] = sum_c x[b,c,hw] * w_pre1[o,c] + b_pre1[o]   (all fp32)
// grid (1024, 3): blockIdx.x = 256-pixel tile, blockIdx.y = 64-o tile
// ---------------------------------------------------------------------------
__global__ __launch_bounds__(256) void k_pre1(
    const float* __restrict__ x, const float* __restrict__ w,
    const float* __restrict__ bias, float* __restrict__ h1)
{
    __shared__ __align__(16) float lw[64 * 192];   // 48 KB [o][c]
    const int tid = threadIdx.x;
    const int obase = blockIdx.y * 64;
    for (int i = tid; i < 64 * 192; i += 256)
        lw[i] = w[obase * 192 + i];
    __syncthreads();

    const int g  = blockIdx.x * 256 + tid;      // global pixel in [0, NB*HW)
    const int b  = g >> 14;
    const int hw = g & (HW - 1);
    const float* xb = x + (size_t)b * DIM * HW + hw;

    float acc[64];
#pragma unroll
    for (int o = 0; o < 64; ++o) acc[o] = bias[obase + o];

    for (int c = 0; c < DIM; c += 4) {
        float xv0 = xb[(size_t)(c + 0) * HW];
        float xv1 = xb[(size_t)(c + 1) * HW];
        float xv2 = xb[(size_t)(c + 2) * HW];
        float xv3 = xb[(size_t)(c + 3) * HW];
#pragma unroll
        for (int o = 0; o < 64; ++o) {
            const float4 wv = *(const float4*)&lw[o * 192 + c];
            acc[o] += wv.x * xv0 + wv.y * xv1 + wv.z * xv2 + wv.w * xv3;
        }
    }
    float* hb = h1 + (size_t)b * DIM * HW + hw;
#pragma unroll
    for (int o = 0; o < 64; ++o) hb[(size_t)(obase + o) * HW] = acc[o];
}

// ---------------------------------------------------------------------------
// K2: depthwise 3x3 (SAME) + bias, LayerNorm over channels, window partition.
// One block per window. Writes p[win, t, c] bf16.
// ---------------------------------------------------------------------------
__global__ __launch_bounds__(256) void k_dwln(
    const float* __restrict__ h1, const float* __restrict__ w_dw,
    const float* __restrict__ b_dw, const float* __restrict__ ln_g,
    const float* __restrict__ ln_b, bf16* __restrict__ p)
{
    __shared__ float tile[64 * 192];      // [pix][ch] post-conv, 48 KB
    __shared__ float patch[32 * 101];     // [ch][10x10 + pad], 12.9 KB
    const int tid = threadIdx.x;
    const int win = blockIdx.x;
    const int b = win >> 8, rem = win & 255;
    const int r0 = (rem >> 4) * 8, c0 = (rem & 15) * 8;

    for (int cc = 0; cc < 6; ++cc) {      // 6 chunks of 32 channels
        for (int i = tid; i < 3200; i += 256) {
            int ch = i / 100, pp = i % 100;
            int pr = pp / 10, pc = pp % 10;
            int gy = r0 - 1 + pr, gx = c0 - 1 + pc;
            float v = 0.f;
            if ((unsigned)gy < 128u && (unsigned)gx < 128u)
                v = h1[(((size_t)b * DIM + cc * 32 + ch) * IMG_H + gy) * IMG_W + gx];
            patch[ch * 101 + pp] = v;
        }
        __syncthreads();
        for (int i = tid; i < 2048; i += 256) {     // 64 pix * 32 ch
            int pix = i >> 5, chl = i & 31;
            int ch = cc * 32 + chl;
            int r = pix >> 3, c = pix & 7;
            float acc = b_dw[ch];
#pragma unroll
            for (int ky = 0; ky < 3; ++ky)
#pragma unroll
                for (int kx = 0; kx < 3; ++kx)
                    acc = fmaf(w_dw[ch * 9 + ky * 3 + kx],
                               patch[chl * 101 + (r + ky) * 10 + (c + kx)], acc);
            tile[pix * 192 + ch] = acc;
        }
        __syncthreads();
    }
    // LayerNorm per pixel over 192 channels: 4 threads per pixel
    const int pix = tid >> 2, sub = tid & 3;
    float s1 = 0.f, s2 = 0.f;
    for (int j = 0; j < 48; ++j) {
        float v = tile[pix * 192 + sub * 48 + j];
        s1 += v; s2 += v * v;
    }
    s1 += __shfl_xor(s1, 1); s2 += __shfl_xor(s2, 1);
    s1 += __shfl_xor(s1, 2); s2 += __shfl_xor(s2, 2);
    float mu  = s1 * (1.f / 192.f);
    float var = fmaxf(s2 * (1.f / 192.f) - mu * mu, 0.f);
    float rstd = rsqrtf(var + LN_EPS);
    bf16* pout = p + ((size_t)win * 64 + pix) * 192 + sub * 48;
    for (int j = 0; j < 48; ++j) {
        int c = sub * 48 + j;
        pout[j] = f2b((tile[pix * 192 + c] - mu) * rstd * ln_g[c] + ln_b[c]);
    }
}

// ---------------------------------------------------------------------------
// K3: per-window QKV + attention, all matmuls via bf16 MFMA 16x16x32.
// One block (256 thr = 4 waves) per window.
// ---------------------------------------------------------------------------
__global__ __launch_bounds__(256) void k_attn(
    const bf16* __restrict__ p, const bf16* __restrict__ wqkvt,
    const float* __restrict__ b_qkv, bf16* __restrict__ a)
{
    __shared__ __align__(16) char smem[142848];
    bf16*  qs = (bf16*)(smem);             // [64][200] 25600 B
    bf16*  ks = (bf16*)(smem + 25600);     // [64][200] 25600 B
    bf16*  vT = (bf16*)(smem + 51200);     // [192][72] 27648 B
    bf16*  ps = (bf16*)(smem + 78848);     // [64][200] 25600 B
    bf16*  wt = (bf16*)(smem + 104448);    // [96][200] 38400 B
    float* ss = (float*)(smem + 78848);    // [64][66] fp32, overlaps ps (dead)
    bf16*  pb = (bf16*)(smem + 104448);    // [64][72], overlaps wt (dead)

    const int tid  = threadIdx.x;
    const int wave = tid >> 6, lane = tid & 63;
    const int lid  = lane & 15, lhi = lane >> 4;
    const int win  = blockIdx.x;
    const f32x4 zero4 = {0.f, 0.f, 0.f, 0.f};

    // stage p window (64 x 192) into padded LDS
    const bf16* pwin = p + (size_t)win * 64 * 192;
    for (int i = tid; i < 1536; i += 256) {
        int r = i / 24, c = (i % 24) * 8;
        *(bh8*)(ps + r * 200 + c) = *(const bh8*)(pwin + r * 192 + c);
    }

    // ---- QKV: (64 x 192) @ (192 x 576), weight pre-transposed [576][192] ----
    const int mb  = (wave >> 1) * 32;   // wave m-tile base (rows)
    const int nbw = (wave & 1) * 48;    // wave n-tile base within 96-col chunk
    for (int nc = 0; nc < 6; ++nc) {    // 6 chunks of 96 output cols
        for (int i = tid; i < 2304; i += 256) {   // stage weight chunk 96x192
            int r = i / 24, c = (i % 24) * 8;
            *(bh8*)(wt + r * 200 + c) =
                *(const bh8*)(wqkvt + (size_t)(nc * 96 + r) * 192 + c);
        }
        __syncthreads();

        f32x4 acc[2][3];
#pragma unroll
        for (int mi = 0; mi < 2; ++mi)
#pragma unroll
            for (int ni = 0; ni < 3; ++ni) {
                float b = b_qkv[nc * 96 + nbw + ni * 16 + lid];
                f32x4 bb = {b, b, b, b};
                acc[mi][ni] = bb;
            }
#pragma unroll
        for (int k8 = 0; k8 < 6; ++k8) {
            bh8 af[2], bfr[3];
#pragma unroll
            for (int mi = 0; mi < 2; ++mi)
                af[mi] = *(const bh8*)(ps + (mb + mi * 16 + lid) * 200 + k8 * 32 + 8 * lhi);
#pragma unroll
            for (int ni = 0; ni < 3; ++ni)
                bfr[ni] = *(const bh8*)(wt + (nbw + ni * 16 + lid) * 200 + k8 * 32 + 8 * lhi);
#pragma unroll
            for (int mi = 0; mi < 2; ++mi)
#pragma unroll
                for (int ni = 0; ni < 3; ++ni)
                    acc[mi][ni] = MFMA16(af[mi], bfr[ni], acc[mi][ni]);
        }
        // writeback: D lane holds col = lid, rows = 4*lhi + reg (within m-tile)
#pragma unroll
        for (int mi = 0; mi < 2; ++mi)
#pragma unroll
            for (int ni = 0; ni < 3; ++ni) {
                const int colg = nc * 96 + nbw + ni * 16 + lid;
#pragma unroll
                for (int r = 0; r < 4; ++r) {
                    const int t = mb + mi * 16 + 4 * lhi + r;
                    float v = acc[mi][ni][r];
                    if (colg < 192)       qs[t * 200 + colg] = f2b(v * ATT_SCALE);
                    else if (colg < 384)  ks[t * 200 + (colg - 192)] = f2b(v);
                    else                  vT[(colg - 384) * 72 + t] = f2b(v);
                }
            }
        __syncthreads();
    }

    // ---- per-head attention ----
    for (int h = 0; h < NHEADS; ++h) {
        // S = Q K^T  (scale folded into Q); wave handles 16-row tile
        bh8 qf = *(const bh8*)(qs + (wave * 16 + lid) * 200 + h * 32 + 8 * lhi);
        f32x4 sacc[4];
#pragma unroll
        for (int ni = 0; ni < 4; ++ni) {
            bh8 kf = *(const bh8*)(ks + (ni * 16 + lid) * 200 + h * 32 + 8 * lhi);
            sacc[ni] = MFMA16(qf, kf, zero4);
        }
#pragma unroll
        for (int ni = 0; ni < 4; ++ni)
#pragma unroll
            for (int r = 0; r < 4; ++r)
                ss[(wave * 16 + 4 * lhi + r) * 66 + ni * 16 + lid] = sacc[ni][r];
        __syncthreads();

        // softmax rows: 4 threads / row, write P as bf16
        {
            const int t = tid >> 2, sub = tid & 3;
            float e[16];
            float mx = -1e30f;
#pragma unroll
            for (int j = 0; j < 16; ++j) mx = fmaxf(mx, ss[t * 66 + sub * 16 + j]);
            mx = fmaxf(mx, __shfl_xor(mx, 1));
            mx = fmaxf(mx, __shfl_xor(mx, 2));
            float sum = 0.f;
#pragma unroll
            for (int j = 0; j < 16; ++j) {
                e[j] = __expf(ss[t * 66 + sub * 16 + j] - mx);
                sum += e[j];
            }
            sum += __shfl_xor(sum, 1);
            sum += __shfl_xor(sum, 2);
            float inv = 1.f / sum;
#pragma unroll
            for (int j = 0; j < 16; ++j)
                pb[t * 72 + sub * 16 + j] = f2b(e[j] * inv);
        }
        __syncthreads();

        // O = P V  (V stored transposed [ch][tok])
#pragma unroll
        for (int nb2 = 0; nb2 < 2; ++nb2) {
            f32x4 oacc = zero4;
#pragma unroll
            for (int kk = 0; kk < 2; ++kk) {
                bh8 pf = *(const bh8*)(pb + (wave * 16 + lid) * 72 + kk * 32 + 8 * lhi);
                bh8 vf = *(const bh8*)(vT + (h * 32 + nb2 * 16 + lid) * 72 + kk * 32 + 8 * lhi);
                oacc = MFMA16(pf, vf, oacc);
            }
#pragma unroll
            for (int r = 0; r < 4; ++r) {
                const int t = wave * 16 + 4 * lhi + r;
                a[((size_t)win * 64 + t) * 192 + h * 32 + nb2 * 16 + lid] = f2b(oacc[r]);
            }
        }
        __syncthreads();
    }
}

// ---------------------------------------------------------------------------
// K4: gMLP (gelu(p@w1+b1)@w2+b2) via MFMA, multiply with attn out in-place.
// One block (4 waves) per window; 12 hidden-chunks of 64.
// ---------------------------------------------------------------------------
__global__ __launch_bounds__(256) void k_gmlp(
    const bf16* __restrict__ p, const bf16* __restrict__ w1t,
    const float* __restrict__ b1, const bf16* __restrict__ w2t,
    const float* __restrict__ b2, bf16* __restrict__ a)
{
    __shared__ __align__(16) char smem[88064];
    bf16* ps  = (bf16*)(smem);             // [64][200] 25600 B
    bf16* w1c = (bf16*)(smem + 25600);     // [64][200] 25600 B
    bf16* w2c = (bf16*)(smem + 51200);     // [192][72] 27648 B
    bf16* hb  = (bf16*)(smem + 78848);     // [64][72]   9216 B

    const int tid  = threadIdx.x;
    const int wave = tid >> 6, lane = tid & 63;
    const int lid  = lane & 15, lhi = lane >> 4;
    const int win  = blockIdx.x;

    const bf16* pwin = p + (size_t)win * 64 * 192;
    for (int i = tid; i < 1536; i += 256) {
        int r = i / 24, c = (i % 24) * 8;
        *(bh8*)(ps + r * 200 + c) = *(const bh8*)(pwin + r * 192 + c);
    }

    f32x4 acc2[12];
#pragma unroll
    for (int ni = 0; ni < 12; ++ni) {
        float b = b2[ni * 16 + lid];
        f32x4 bb = {b, b, b, b};
        acc2[ni] = bb;
    }
    const int mb = (wave >> 1) * 32, nb = (wave & 1) * 32;

    for (int hc = 0; hc < 12; ++hc) {
        for (int i = tid; i < 1536; i += 256) {   // w1 chunk [64 hid][192 k]
            int r = i / 24, c = (i % 24) * 8;
            *(bh8*)(w1c + r * 200 + c) =
                *(const bh8*)(w1t + (size_t)(hc * 64 + r) * 192 + c);
        }
        for (int i = tid; i < 1536; i += 256) {   // w2 chunk [192 out][64 k]
            int r = i / 8, c = (i % 8) * 8;
            *(bh8*)(w2c + r * 72 + c) =
                *(const bh8*)(w2t + (size_t)r * 768 + hc * 64 + c);
        }
        __syncthreads();

        // GEMM1: hidden chunk (64 x 64), wave tile 32 x 32
        f32x4 acc1[2][2];
#pragma unroll
        for (int mi = 0; mi < 2; ++mi)
#pragma unroll
            for (int ni = 0; ni < 2; ++ni) {
                float b = b1[hc * 64 + nb + ni * 16 + lid];
                f32x4 bb = {b, b, b, b};
                acc1[mi][ni] = bb;
            }
#pragma unroll
        for (int k8 = 0; k8 < 6; ++k8) {
            bh8 af0 = *(const bh8*)(ps + (mb + lid) * 200 + k8 * 32 + 8 * lhi);
            bh8 af1 = *(const bh8*)(ps + (mb + 16 + lid) * 200 + k8 * 32 + 8 * lhi);
            bh8 bf0 = *(const bh8*)(w1c + (nb + lid) * 200 + k8 * 32 + 8 * lhi);
            bh8 bf1 = *(const bh8*)(w1c + (nb + 16 + lid) * 200 + k8 * 32 + 8 * lhi);
            acc1[0][0] = MFMA16(af0, bf0, acc1[0][0]);
            acc1[0][1] = MFMA16(af0, bf1, acc1[0][1]);
            acc1[1][0] = MFMA16(af1, bf0, acc1[1][0]);
            acc1[1][1] = MFMA16(af1, bf1, acc1[1][1]);
        }
        // exact GELU -> hb (bf16)
#pragma unroll
        for (int mi = 0; mi < 2; ++mi)
#pragma unroll
            for (int ni = 0; ni < 2; ++ni)
#pragma unroll
                for (int r = 0; r < 4; ++r) {
                    int row = mb + mi * 16 + 4 * lhi + r;
                    int col = nb + ni * 16 + lid;
                    float xv = acc1[mi][ni][r];
                    hb[row * 72 + col] =
                        f2b(0.5f * xv * (1.f + erff(xv * 0.70710678118654752f)));
                }
        __syncthreads();

        // GEMM2: acc2 (16 rows x 192 cols per wave) += hb @ w2chunk
#pragma unroll
        for (int kk = 0; kk < 2; ++kk) {
            bh8 hf = *(const bh8*)(hb + (wave * 16 + lid) * 72 + kk * 32 + 8 * lhi);
#pragma unroll
            for (int ni = 0; ni < 12; ++ni) {
                bh8 wf = *(const bh8*)(w2c + (ni * 16 + lid) * 72 + kk * 32 + 8 * lhi);
                acc2[ni] = MFMA16(hf, wf, acc2[ni]);
            }
        }
        __syncthreads();
    }

    // epilogue: out = attn * gmlp, in-place on a
    bf16* awin = a + (size_t)win * 64 * 192;
#pragma unroll
    for (int ni = 0; ni < 12; ++ni)
#pragma unroll
        for (int r = 0; r < 4; ++r) {
            int t = wave * 16 + 4 * lhi + r;
            int col = ni * 16 + lid;
            size_t idx = (size_t)t * 192 + col;
            awin[idx] = f2b(acc2[ni][r] * b2f(awin[idx]));
        }
}

// ---------------------------------------------------------------------------
// K5: proj 1x1 + bias + residual via bf16 MFMA. Block = 2 adjacent windows
// (128 tokens), grid NWIN/2 = 2048, 4 waves. w_proj fp32 staged+cast to bf16
// in LDS ([o][c] layout is already the MFMA B layout [n][k] -> no transpose).
// Epilogue: acc -> LDS (overlay) -> coalesced 64B NCHW write + residual.
// ---------------------------------------------------------------------------
__global__ __launch_bounds__(256) void k_proj(
    const bf16* __restrict__ m, const float* __restrict__ wp,
    const float* __restrict__ b_proj, const float* __restrict__ x,
    float* __restrict__ out)
{
    __shared__ __align__(16) char smem[128000];
    bf16*  mw = (bf16*)(smem);             // [128][200] 51200 B
    bf16*  wl = (bf16*)(smem + 51200);     // [192][200] 76800 B
    float* ot = (float*)(smem);            // [128][193] 98816 B, overlay

    const int tid  = threadIdx.x;
    const int wave = tid >> 6, lane = tid & 63;
    const int lid  = lane & 15, lhi = lane >> 4;
    const int bp   = blockIdx.x;           // [0, 2048)
    const int b    = bp >> 7, rem = bp & 127;
    const int wr   = rem >> 3, wcp = rem & 7;
    const int win0 = b * 256 + wr * 16 + wcp * 2;   // win1 = win0+1 contiguous
    const int r0   = wr * 8, c0 = wcp * 16;

    // stage 128 tokens (2 windows, contiguous in m)
    const bf16* msrc = m + (size_t)win0 * 64 * 192;
    for (int i = tid; i < 3072; i += 256) {
        int r = i / 24, c = (i % 24) * 8;
        *(bh8*)(mw + r * 200 + c) = *(const bh8*)(msrc + (size_t)r * 192 + c);
    }
    // stage full w_proj with fp32 -> bf16 cast (192x192, float4 loads)
    for (int i = tid; i < 9216; i += 256) {
        int r = i / 48, c = (i % 48) * 4;
        float4 v = *(const float4*)(wp + (size_t)r * 192 + c);
        bf16* d = wl + r * 200 + c;
        d[0] = f2b(v.x); d[1] = f2b(v.y); d[2] = f2b(v.z); d[3] = f2b(v.w);
    }
    __syncthreads();

    // wave computes 32 tokens x 192 o
    const int mb = wave * 32;
    f32x4 acc[2][12];
#pragma unroll
    for (int ni = 0; ni < 12; ++ni) {
        float bv = b_proj[ni * 16 + lid];
        f32x4 bb = {bv, bv, bv, bv};
        acc[0][ni] = bb;
        acc[1][ni] = bb;
    }
#pragma unroll
    for (int k8 = 0; k8 < 6; ++k8) {
        bh8 af0 = *(const bh8*)(mw + (mb + lid) * 200 + k8 * 32 + 8 * lhi);
        bh8 af1 = *(const bh8*)(mw + (mb + 16 + lid) * 200 + k8 * 32 + 8 * lhi);
#pragma unroll
        for (int ni = 0; ni < 12; ++ni) {
            bh8 bfr = *(const bh8*)(wl + (ni * 16 + lid) * 200 + k8 * 32 + 8 * lhi);
            acc[0][ni] = MFMA16(af0, bfr, acc[0][ni]);
            acc[1][ni] = MFMA16(af1, bfr, acc[1][ni]);
        }
    }
    __syncthreads();   // mw/wl dead; overlay ot

#pragma unroll
    for (int mi = 0; mi < 2; ++mi)
#pragma unroll
        for (int ni = 0; ni < 12; ++ni)
#pragma unroll
            for (int r = 0; r < 4; ++r)
                ot[(mb + mi * 16 + 4 * lhi + r) * 193 + ni * 16 + lid] = acc[mi][ni][r];
    __syncthreads();

    // coalesced NCHW write: region = 8 rows x 16 cols (two windows), 192 o
    for (int i = tid; i < 24576; i += 256) {
        int o = i >> 7, pix = i & 127;
        int r = pix >> 4, cc = pix & 15;
        int trow = ((cc >> 3) << 6) + r * 8 + (cc & 7);   // token row in ot
        size_t idx = (((size_t)b * DIM + o) * IMG_H + r0 + r) * IMG_W + c0 + cc;
        out[idx] = ot[trow * 193 + o] + x[idx];           // + residual
    }
}

// ---------------------------------------------------------------------------
extern "C" void kernel_launch(void* const* d_in, const int* in_sizes, int n_in,
                              void* d_out, int out_size, void* d_ws, size_t ws_size,
                              hipStream_t stream)
{
    const float* x      = (const float*)d_in[0];
    const float* w_pre1 = (const float*)d_in[1];
    const float* b_pre1 = (const float*)d_in[2];
    const float* w_dw   = (const float*)d_in[3];
    const float* b_dw   = (const float*)d_in[4];
    const float* ln_g   = (const float*)d_in[5];
    const float* ln_b   = (const float*)d_in[6];
    const float* w_qkv  = (const float*)d_in[7];
    const float* b_qkv  = (const float*)d_in[8];
    const float* w1     = (const float*)d_in[9];
    const float* b1     = (const float*)d_in[10];
    const float* w2     = (const float*)d_in[11];
    const float* b2     = (const float*)d_in[12];
    const float* w_proj = (const float*)d_in[13];
    const float* b_proj = (const float*)d_in[14];
    float* out = (float*)d_out;

    const size_t NELEM = (size_t)NB * DIM * HW;   // 50,331,648
    // h1 lives fp32 inside d_out (dead before k_proj overwrites d_out)
    float* h1 = (float*)d_out;
    bf16* p = (bf16*)d_ws;           // LN'd window tokens (win, t, c)
    bf16* a = p + NELEM;             // attn out, then attn*gmlp (in-place)
    bf16* wqkvt = a + NELEM;         // [576][192] transposed bf16 weights
    bf16* w1t   = wqkvt + 3 * DIM * DIM;   // [768][192]
    bf16* w2t   = w1t + 4 * DIM * DIM;     // [192][768]

    // weight prep (transpose + cast); independent of data path
    k_prep<<<dim3(18, 6),  256, 0, stream>>>(w_qkv, wqkvt, DIM, 3 * DIM);
    k_prep<<<dim3(24, 6),  256, 0, stream>>>(w1, w1t, DIM, 4 * DIM);
    k_prep<<<dim3(6, 24),  256, 0, stream>>>(w2, w2t, 4 * DIM, DIM);

    k_pre1<<<dim3(1024, 3), 256, 0, stream>>>(x, w_pre1, b_pre1, h1);
    k_dwln<<<dim3(NWIN), 256, 0, stream>>>(h1, w_dw, b_dw, ln_g, ln_b, p);
    k_attn<<<dim3(NWIN), 256, 0, stream>>>(p, wqkvt, b_qkv, a);
    k_gmlp<<<dim3(NWIN), 256, 0, stream>>>(p, w1t, b1, w2t, b2, a);
    k_proj<<<dim3(NWIN / 2), 256, 0, stream>>>(a, w_proj, b_proj, x, out);
}

// Round 5
// 2157.664 us; speedup vs baseline: 4.8678x; 1.2624x over previous
//
#include <hip/hip_runtime.h>
#include <hip/hip_bf16.h>
#include <math.h>

// RSWABlock: x:(16,192,128,128) fp32 -> pre1(1x1) -> dw3x3 -> LN(ch) ->
// 8x8 windows -> (attention * gMLP) -> merge -> proj(1x1) -> + x
// Round 7: k_gmlp -> 2 windows/block, 8 waves (barrier+staging per window
// halved); k_attn -> 1 head per wave (6 waves), in-register softmax,
// zero barriers in the head phase.

#define DIM    192
#define IMG_H  128
#define IMG_W  128
#define HW     16384        // 128*128
#define NB     16           // batch
#define NWIN   4096         // 16 batches * 16 * 16 windows
#define NHEADS 6
#define HDIM   32
#define ATT_SCALE 0.17677669529663687f  // 32^-0.5
#define LN_EPS 1e-6f

typedef __hip_bfloat16 bf16;
__device__ __forceinline__ float b2f(bf16 v) { return __bfloat162float(v); }
__device__ __forceinline__ bf16  f2b(float v) { return __float2bfloat16(v); }

typedef __bf16 bh8 __attribute__((ext_vector_type(8)));
typedef float  f32x4 __attribute__((ext_vector_type(4)));
#define MFMA16(a, b, c) __builtin_amdgcn_mfma_f32_16x16x32_bf16((a), (b), (c), 0, 0, 0)

// ---------------------------------------------------------------------------
// K0: weight prep — dst[n*K + k] = bf16(src[k*N + n])   (transpose + cast)
// ---------------------------------------------------------------------------
__global__ __launch_bounds__(256) void k_prep(
    const float* __restrict__ src, bf16* __restrict__ dst, int K, int N)
{
    __shared__ float t[32][33];
    const int tid = threadIdx.x;
    const int lx = tid & 31, ly = tid >> 5;
    const int n0 = blockIdx.x * 32, k0 = blockIdx.y * 32;
    for (int r = ly; r < 32; r += 8)
        t[r][lx] = src[(size_t)(k0 + r) * N + n0 + lx];
    __syncthreads();
    for (int r = ly; r < 32; r += 8)
        dst[(size_t)(n0 + r) * K + k0 + lx] = f2b(t[lx][r]);
}

// ---------------------------------------------------------------------------
// K1: h1[b,o,hw] = sum_c x[b,c,hw] * w_pre1[o,c] + b_pre1[o]   (all fp32)
// ---------------------------------------------------------------------------
__global__ __launch_bounds__(256) void k_pre1(
    const float* __restrict__ x, const float* __restrict__ w,
    const float* __restrict__ bias, float* __restrict__ h1)
{
    __shared__ __align__(16) float lw[64 * 192];   // 48 KB [o][c]
    const int tid = threadIdx.x;
    const int obase = blockIdx.y * 64;
    for (int i = tid; i < 64 * 192; i += 256)
        lw[i] = w[obase * 192 + i];
    __syncthreads();

    const int g  = blockIdx.x * 256 + tid;      // global pixel in [0, NB*HW)
    const int b  = g >> 14;
    const int hw = g & (HW - 1);
    const float* xb = x + (size_t)b * DIM * HW + hw;

    float acc[64];
#pragma unroll
    for (int o = 0; o < 64; ++o) acc[o] = bias[obase + o];

    for (int c = 0; c < DIM; c += 4) {
        float xv0 = xb[(size_t)(c + 0) * HW];
        float xv1 = xb[(size_t)(c + 1) * HW];
        float xv2 = xb[(size_t)(c + 2) * HW];
        float xv3 = xb[(size_t)(c + 3) * HW];
#pragma unroll
        for (int o = 0; o < 64; ++o) {
            const float4 wv = *(const float4*)&lw[o * 192 + c];
            acc[o] += wv.x * xv0 + wv.y * xv1 + wv.z * xv2 + wv.w * xv3;
        }
    }
    float* hb = h1 + (size_t)b * DIM * HW + hw;
#pragma unroll
    for (int o = 0; o < 64; ++o) hb[(size_t)(obase + o) * HW] = acc[o];
}

// ---------------------------------------------------------------------------
// K2: depthwise 3x3 (SAME) + bias, LayerNorm over channels, window partition.
// ---------------------------------------------------------------------------
__global__ __launch_bounds__(256) void k_dwln(
    const float* __restrict__ h1, const float* __restrict__ w_dw,
    const float* __restrict__ b_dw, const float* __restrict__ ln_g,
    const float* __restrict__ ln_b, bf16* __restrict__ p)
{
    __shared__ float tile[64 * 192];      // [pix][ch] post-conv, 48 KB
    __shared__ float patch[32 * 101];     // [ch][10x10 + pad], 12.9 KB
    const int tid = threadIdx.x;
    const int win = blockIdx.x;
    const int b = win >> 8, rem = win & 255;
    const int r0 = (rem >> 4) * 8, c0 = (rem & 15) * 8;

    for (int cc = 0; cc < 6; ++cc) {      // 6 chunks of 32 channels
        for (int i = tid; i < 3200; i += 256) {
            int ch = i / 100, pp = i % 100;
            int pr = pp / 10, pc = pp % 10;
            int gy = r0 - 1 + pr, gx = c0 - 1 + pc;
            float v = 0.f;
            if ((unsigned)gy < 128u && (unsigned)gx < 128u)
                v = h1[(((size_t)b * DIM + cc * 32 + ch) * IMG_H + gy) * IMG_W + gx];
            patch[ch * 101 + pp] = v;
        }
        __syncthreads();
        for (int i = tid; i < 2048; i += 256) {     // 64 pix * 32 ch
            int pix = i >> 5, chl = i & 31;
            int ch = cc * 32 + chl;
            int r = pix >> 3, c = pix & 7;
            float acc = b_dw[ch];
#pragma unroll
            for (int ky = 0; ky < 3; ++ky)
#pragma unroll
                for (int kx = 0; kx < 3; ++kx)
                    acc = fmaf(w_dw[ch * 9 + ky * 3 + kx],
                               patch[chl * 101 + (r + ky) * 10 + (c + kx)], acc);
            tile[pix * 192 + ch] = acc;
        }
        __syncthreads();
    }
    // LayerNorm per pixel over 192 channels: 4 threads per pixel
    const int pix = tid >> 2, sub = tid & 3;
    float s1 = 0.f, s2 = 0.f;
    for (int j = 0; j < 48; ++j) {
        float v = tile[pix * 192 + sub * 48 + j];
        s1 += v; s2 += v * v;
    }
    s1 += __shfl_xor(s1, 1); s2 += __shfl_xor(s2, 1);
    s1 += __shfl_xor(s1, 2); s2 += __shfl_xor(s2, 2);
    float mu  = s1 * (1.f / 192.f);
    float var = fmaxf(s2 * (1.f / 192.f) - mu * mu, 0.f);
    float rstd = rsqrtf(var + LN_EPS);
    bf16* pout = p + ((size_t)win * 64 + pix) * 192 + sub * 48;
    for (int j = 0; j < 48; ++j) {
        int c = sub * 48 + j;
        pout[j] = f2b((tile[pix * 192 + c] - mu) * rstd * ln_g[c] + ln_b[c]);
    }
}

// ---------------------------------------------------------------------------
// K3: per-window QKV + attention. 6 waves (384 thr), one head per wave in
// the attention phase; softmax fully in registers (shfl over lid group).
// LDS: qs[64][200], ks[64][200], vT[192][72]; staging ps[64][200]+wt[96][200]
// (dead after QKV) overlaid by per-wave P buffers pbw[6][64][72].
// ---------------------------------------------------------------------------
__global__ __launch_bounds__(384) void k_attn(
    const bf16* __restrict__ p, const bf16* __restrict__ wqkvt,
    const float* __restrict__ b_qkv, bf16* __restrict__ a)
{
    __shared__ __align__(16) char smem[142848];
    bf16*  qs = (bf16*)(smem);             // [64][200] 25600 B
    bf16*  ks = (bf16*)(smem + 25600);     // [64][200] 25600 B
    bf16*  vT = (bf16*)(smem + 51200);     // [192][72] 27648 B
    bf16*  ps = (bf16*)(smem + 78848);     // [64][200] 25600 B
    bf16*  wt = (bf16*)(smem + 104448);    // [96][200] 38400 B
    // head-phase overlay (ps/wt dead): 6 x [64][72] bf16 = 55296 B
    bf16*  pbase = (bf16*)(smem + 78848);

    const int tid  = threadIdx.x;
    const int wave = tid >> 6, lane = tid & 63;
    const int lid  = lane & 15, lhi = lane >> 4;
    const int win  = blockIdx.x;
    const f32x4 zero4 = {0.f, 0.f, 0.f, 0.f};

    // stage p window (64 x 192) into padded LDS
    const bf16* pwin = p + (size_t)win * 64 * 192;
    for (int i = tid; i < 1536; i += 384) {
        int r = i / 24, c = (i % 24) * 8;
        *(bh8*)(ps + r * 200 + c) = *(const bh8*)(pwin + r * 192 + c);
    }

    // ---- QKV: (64 x 192) @ (192 x 576), weight pre-transposed [576][192] ----
    // 6 waves: 2 m-tiles x 3 n-tiles of 32x32 per 96-col chunk
    const int mb  = (wave / 3) * 32;
    const int nbw = (wave % 3) * 32;
    for (int nc = 0; nc < 6; ++nc) {    // 6 chunks of 96 output cols
        for (int i = tid; i < 2304; i += 384) {   // stage weight chunk 96x192
            int r = i / 24, c = (i % 24) * 8;
            *(bh8*)(wt + r * 200 + c) =
                *(const bh8*)(wqkvt + (size_t)(nc * 96 + r) * 192 + c);
        }
        __syncthreads();

        f32x4 acc[2][2];
#pragma unroll
        for (int mi = 0; mi < 2; ++mi)
#pragma unroll
            for (int ni = 0; ni < 2; ++ni) {
                float b = b_qkv[nc * 96 + nbw + ni * 16 + lid];
                f32x4 bb = {b, b, b, b};
                acc[mi][ni] = bb;
            }
#pragma unroll
        for (int k8 = 0; k8 < 6; ++k8) {
            bh8 af[2], bfr[2];
#pragma unroll
            for (int mi = 0; mi < 2; ++mi)
                af[mi] = *(const bh8*)(ps + (mb + mi * 16 + lid) * 200 + k8 * 32 + 8 * lhi);
#pragma unroll
            for (int ni = 0; ni < 2; ++ni)
                bfr[ni] = *(const bh8*)(wt + (nbw + ni * 16 + lid) * 200 + k8 * 32 + 8 * lhi);
#pragma unroll
            for (int mi = 0; mi < 2; ++mi)
#pragma unroll
                for (int ni = 0; ni < 2; ++ni)
                    acc[mi][ni] = MFMA16(af[mi], bfr[ni], acc[mi][ni]);
        }
        // writeback: D lane holds col = lid, rows = 4*lhi + reg (within m-tile)
#pragma unroll
        for (int mi = 0; mi < 2; ++mi)
#pragma unroll
            for (int ni = 0; ni < 2; ++ni) {
                const int colg = nc * 96 + nbw + ni * 16 + lid;
#pragma unroll
                for (int r = 0; r < 4; ++r) {
                    const int t = mb + mi * 16 + 4 * lhi + r;
                    float v = acc[mi][ni][r];
                    if (colg < 192)       qs[t * 200 + colg] = f2b(v * ATT_SCALE);
                    else if (colg < 384)  ks[t * 200 + (colg - 192)] = f2b(v);
                    else                  vT[(colg - 384) * 72 + t] = f2b(v);
                }
            }
        __syncthreads();
    }

    // ---- attention: one head per wave, no barriers ----
    const int h = wave;                    // NHEADS == 6 == waves
    bf16* pw = pbase + wave * (64 * 72);   // wave-private P buffer

    // S = Q K^T (scale folded into Q): full 64x64 per wave, 16 MFMA
    f32x4 sacc[4][4];
    {
        bh8 qf[4], kf[4];
#pragma unroll
        for (int mi = 0; mi < 4; ++mi)
            qf[mi] = *(const bh8*)(qs + (mi * 16 + lid) * 200 + h * 32 + 8 * lhi);
#pragma unroll
        for (int ni = 0; ni < 4; ++ni)
            kf[ni] = *(const bh8*)(ks + (ni * 16 + lid) * 200 + h * 32 + 8 * lhi);
#pragma unroll
        for (int mi = 0; mi < 4; ++mi)
#pragma unroll
            for (int ni = 0; ni < 4; ++ni)
                sacc[mi][ni] = MFMA16(qf[mi], kf[ni], zero4);
    }

    // softmax per row, in registers. Row q = mi*16+4*lhi+r lives in the 16
    // lanes sharing lhi (cols ni*16+lid) -> shfl_xor 1,2,4,8 reduces it.
#pragma unroll
    for (int mi = 0; mi < 4; ++mi)
#pragma unroll
        for (int r = 0; r < 4; ++r) {
            float mx = fmaxf(fmaxf(sacc[mi][0][r], sacc[mi][1][r]),
                             fmaxf(sacc[mi][2][r], sacc[mi][3][r]));
            mx = fmaxf(mx, __shfl_xor(mx, 1));
            mx = fmaxf(mx, __shfl_xor(mx, 2));
            mx = fmaxf(mx, __shfl_xor(mx, 4));
            mx = fmaxf(mx, __shfl_xor(mx, 8));
            float e0 = __expf(sacc[mi][0][r] - mx);
            float e1 = __expf(sacc[mi][1][r] - mx);
            float e2 = __expf(sacc[mi][2][r] - mx);
            float e3 = __expf(sacc[mi][3][r] - mx);
            float sum = e0 + e1 + e2 + e3;
            sum += __shfl_xor(sum, 1);
            sum += __shfl_xor(sum, 2);
            sum += __shfl_xor(sum, 4);
            sum += __shfl_xor(sum, 8);
            float inv = 1.f / sum;
            sacc[mi][0][r] = e0 * inv;
            sacc[mi][1][r] = e1 * inv;
            sacc[mi][2][r] = e2 * inv;
            sacc[mi][3][r] = e3 * inv;
        }

    // P -> wave-private LDS (transpose from C-layout to A-frag layout)
#pragma unroll
    for (int mi = 0; mi < 4; ++mi)
#pragma unroll
        for (int ni = 0; ni < 4; ++ni)
#pragma unroll
            for (int r = 0; r < 4; ++r)
                pw[(mi * 16 + 4 * lhi + r) * 72 + ni * 16 + lid] = f2b(sacc[mi][ni][r]);
    asm volatile("s_waitcnt lgkmcnt(0)" ::: "memory");
    __builtin_amdgcn_sched_barrier(0);

    // O = P V  (V stored transposed [ch][tok]); 16 MFMA
    f32x4 oacc[4][2];
#pragma unroll
    for (int mi = 0; mi < 4; ++mi)
#pragma unroll
        for (int nb2 = 0; nb2 < 2; ++nb2) oacc[mi][nb2] = zero4;
#pragma unroll
    for (int kk = 0; kk < 2; ++kk) {
        bh8 pf[4];
#pragma unroll
        for (int mi = 0; mi < 4; ++mi)
            pf[mi] = *(const bh8*)(pw + (mi * 16 + lid) * 72 + kk * 32 + 8 * lhi);
#pragma unroll
        for (int nb2 = 0; nb2 < 2; ++nb2) {
            bh8 vf = *(const bh8*)(vT + (h * 32 + nb2 * 16 + lid) * 72 + kk * 32 + 8 * lhi);
#pragma unroll
            for (int mi = 0; mi < 4; ++mi)
                oacc[mi][nb2] = MFMA16(pf[mi], vf, oacc[mi][nb2]);
        }
    }
#pragma unroll
    for (int mi = 0; mi < 4; ++mi)
#pragma unroll
        for (int nb2 = 0; nb2 < 2; ++nb2)
#pragma unroll
            for (int r = 0; r < 4; ++r) {
                const int t = mi * 16 + 4 * lhi + r;
                a[((size_t)win * 64 + t) * 192 + h * 32 + nb2 * 16 + lid] =
                    f2b(oacc[mi][nb2][r]);
            }
}

// ---------------------------------------------------------------------------
// K4: gMLP (gelu(p@w1+b1)@w2+b2) via MFMA, multiply with attn out in-place.
// 2 windows per block (128 tokens), 8 waves (512 thr), grid NWIN/2 = 2048.
// Per hidden-chunk (12 x 64): stage w1/w2 chunks once for BOTH windows.
// ---------------------------------------------------------------------------
__global__ __launch_bounds__(512) void k_gmlp(
    const bf16* __restrict__ p, const bf16* __restrict__ w1t,
    const float* __restrict__ b1, const bf16* __restrict__ w2t,
    const float* __restrict__ b2, bf16* __restrict__ a)
{
    __shared__ __align__(16) char smem[122880];
    bf16* ps  = (bf16*)(smem);             // [128][200] 51200 B
    bf16* w1c = (bf16*)(smem + 51200);     // [64][200]  25600 B
    bf16* w2c = (bf16*)(smem + 76800);     // [192][72]  27648 B
    bf16* hb  = (bf16*)(smem + 104448);    // [128][72]  18432 B

    const int tid  = threadIdx.x;
    const int wave = tid >> 6, lane = tid & 63;
    const int lid  = lane & 15, lhi = lane >> 4;
    const int win0 = blockIdx.x * 2;       // two contiguous windows

    const bf16* pwin = p + (size_t)win0 * 64 * 192;
    for (int i = tid; i < 3072; i += 512) {
        int r = i / 24, c = (i % 24) * 8;
        *(bh8*)(ps + r * 200 + c) = *(const bh8*)(pwin + (size_t)r * 192 + c);
    }

    f32x4 acc2[12];
#pragma unroll
    for (int ni = 0; ni < 12; ++ni) {
        float b = b2[ni * 16 + lid];
        f32x4 bb = {b, b, b, b};
        acc2[ni] = bb;
    }
    // GEMM1 wave tiles: 4 m x 2 n of 32x32 over the 128x64 chunk output
    const int mb = (wave >> 1) * 32, nb = (wave & 1) * 32;

    for (int hc = 0; hc < 12; ++hc) {
        for (int i = tid; i < 1536; i += 512) {   // w1 chunk [64 hid][192 k]
            int r = i / 24, c = (i % 24) * 8;
            *(bh8*)(w1c + r * 200 + c) =
                *(const bh8*)(w1t + (size_t)(hc * 64 + r) * 192 + c);
        }
        for (int i = tid; i < 1536; i += 512) {   // w2 chunk [192 out][64 k]
            int r = i / 8, c = (i % 8) * 8;
            *(bh8*)(w2c + r * 72 + c) =
                *(const bh8*)(w2t + (size_t)r * 768 + hc * 64 + c);
        }
        __syncthreads();

        // GEMM1: hidden chunk (128 x 64), wave tile 32 x 32
        f32x4 acc1[2][2];
#pragma unroll
        for (int mi = 0; mi < 2; ++mi)
#pragma unroll
            for (int ni = 0; ni < 2; ++ni) {
                float b = b1[hc * 64 + nb + ni * 16 + lid];
                f32x4 bb = {b, b, b, b};
                acc1[mi][ni] = bb;
            }
#pragma unroll
        for (int k8 = 0; k8 < 6; ++k8) {
            bh8 af0 = *(const bh8*)(ps + (mb + lid) * 200 + k8 * 32 + 8 * lhi);
            bh8 af1 = *(const bh8*)(ps + (mb + 16 + lid) * 200 + k8 * 32 + 8 * lhi);
            bh8 bf0 = *(const bh8*)(w1c + (nb + lid) * 200 + k8 * 32 + 8 * lhi);
            bh8 bf1 = *(const bh8*)(w1c + (nb + 16 + lid) * 200 + k8 * 32 + 8 * lhi);
            acc1[0][0] = MFMA16(af0, bf0, acc1[0][0]);
            acc1[0][1] = MFMA16(af0, bf1, acc1[0][1]);
            acc1[1][0] = MFMA16(af1, bf0, acc1[1][0]);
            acc1[1][1] = MFMA16(af1, bf1, acc1[1][1]);
        }
        // exact GELU -> hb (bf16)
#pragma unroll
        for (int mi = 0; mi < 2; ++mi)
#pragma unroll
            for (int ni = 0; ni < 2; ++ni)
#pragma unroll
                for (int r = 0; r < 4; ++r) {
                    int row = mb + mi * 16 + 4 * lhi + r;
                    int col = nb + ni * 16 + lid;
                    float xv = acc1[mi][ni][r];
                    hb[row * 72 + col] =
                        f2b(0.5f * xv * (1.f + erff(xv * 0.70710678118654752f)));
                }
        __syncthreads();

        // GEMM2: acc2 (16 rows x 192 cols per wave) += hb @ w2chunk
#pragma unroll
        for (int kk = 0; kk < 2; ++kk) {
            bh8 hf = *(const bh8*)(hb + (wave * 16 + lid) * 72 + kk * 32 + 8 * lhi);
#pragma unroll
            for (int ni = 0; ni < 12; ++ni) {
                bh8 wf = *(const bh8*)(w2c + (ni * 16 + lid) * 72 + kk * 32 + 8 * lhi);
                acc2[ni] = MFMA16(hf, wf, acc2[ni]);
            }
        }
        __syncthreads();
    }

    // epilogue: out = attn * gmlp, in-place on a (rows 0..127 of 2 windows)
    bf16* awin = a + (size_t)win0 * 64 * 192;
#pragma unroll
    for (int ni = 0; ni < 12; ++ni)
#pragma unroll
        for (int r = 0; r < 4; ++r) {
            int t = wave * 16 + 4 * lhi + r;
            int col = ni * 16 + lid;
            size_t idx = (size_t)t * 192 + col;
            awin[idx] = f2b(acc2[ni][r] * b2f(awin[idx]));
        }
}

// ---------------------------------------------------------------------------
// K5: proj 1x1 + bias + residual via bf16 MFMA. Block = 2 adjacent windows
// (128 tokens), grid NWIN/2 = 2048, 4 waves. w_proj fp32 staged+cast to bf16
// in LDS. Epilogue: acc -> LDS overlay -> coalesced NCHW write + residual.
// ---------------------------------------------------------------------------
__global__ __launch_bounds__(256) void k_proj(
    const bf16* __restrict__ m, const float* __restrict__ wp,
    const float* __restrict__ b_proj, const float* __restrict__ x,
    float* __restrict__ out)
{
    __shared__ __align__(16) char smem[128000];
    bf16*  mw = (bf16*)(smem);             // [128][200] 51200 B
    bf16*  wl = (bf16*)(smem + 51200);     // [192][200] 76800 B
    float* ot = (float*)(smem);            // [128][193] 98816 B, overlay

    const int tid  = threadIdx.x;
    const int wave = tid >> 6, lane = tid & 63;
    const int lid  = lane & 15, lhi = lane >> 4;
    const int bp   = blockIdx.x;           // [0, 2048)
    const int b    = bp >> 7, rem = bp & 127;
    const int wr   = rem >> 3, wcp = rem & 7;
    const int win0 = b * 256 + wr * 16 + wcp * 2;   // win1 = win0+1 contiguous
    const int r0   = wr * 8, c0 = wcp * 16;

    // stage 128 tokens (2 windows, contiguous in m)
    const bf16* msrc = m + (size_t)win0 * 64 * 192;
    for (int i = tid; i < 3072; i += 256) {
        int r = i / 24, c = (i % 24) * 8;
        *(bh8*)(mw + r * 200 + c) = *(const bh8*)(msrc + (size_t)r * 192 + c);
    }
    // stage full w_proj with fp32 -> bf16 cast (192x192, float4 loads)
    for (int i = tid; i < 9216; i += 256) {
        int r = i / 48, c = (i % 48) * 4;
        float4 v = *(const float4*)(wp + (size_t)r * 192 + c);
        bf16* d = wl + r * 200 + c;
        d[0] = f2b(v.x); d[1] = f2b(v.y); d[2] = f2b(v.z); d[3] = f2b(v.w);
    }
    __syncthreads();

    // wave computes 32 tokens x 192 o
    const int mb = wave * 32;
    f32x4 acc[2][12];
#pragma unroll
    for (int ni = 0; ni < 12; ++ni) {
        float bv = b_proj[ni * 16 + lid];
        f32x4 bb = {bv, bv, bv, bv};
        acc[0][ni] = bb;
        acc[1][ni] = bb;
    }
#pragma unroll
    for (int k8 = 0; k8 < 6; ++k8) {
        bh8 af0 = *(const bh8*)(mw + (mb + lid) * 200 + k8 * 32 + 8 * lhi);
        bh8 af1 = *(const bh8*)(mw + (mb + 16 + lid) * 200 + k8 * 32 + 8 * lhi);
#pragma unroll
        for (int ni = 0; ni < 12; ++ni) {
            bh8 bfr = *(const bh8*)(wl + (ni * 16 + lid) * 200 + k8 * 32 + 8 * lhi);
            acc[0][ni] = MFMA16(af0, bfr, acc[0][ni]);
            acc[1][ni] = MFMA16(af1, bfr, acc[1][ni]);
        }
    }
    __syncthreads();   // mw/wl dead; overlay ot

#pragma unroll
    for (int mi = 0; mi < 2; ++mi)
#pragma unroll
        for (int ni = 0; ni < 12; ++ni)
#pragma unroll
            for (int r = 0; r < 4; ++r)
                ot[(mb + mi * 16 + 4 * lhi + r) * 193 + ni * 16 + lid] = acc[mi][ni][r];
    __syncthreads();

    // coalesced NCHW write: region = 8 rows x 16 cols (two windows), 192 o
    for (int i = tid; i < 24576; i += 256) {
        int o = i >> 7, pix = i & 127;
        int r = pix >> 4, cc = pix & 15;
        int trow = ((cc >> 3) << 6) + r * 8 + (cc & 7);   // token row in ot
        size_t idx = (((size_t)b * DIM + o) * IMG_H + r0 + r) * IMG_W + c0 + cc;
        out[idx] = ot[trow * 193 + o] + x[idx];           // + residual
    }
}

// ---------------------------------------------------------------------------
extern "C" void kernel_launch(void* const* d_in, const int* in_sizes, int n_in,
                              void* d_out, int out_size, void* d_ws, size_t ws_size,
                              hipStream_t stream)
{
    const float* x      = (const float*)d_in[0];
    const float* w_pre1 = (const float*)d_in[1];
    const float* b_pre1 = (const float*)d_in[2];
    const float* w_dw   = (const float*)d_in[3];
    const float* b_dw   = (const float*)d_in[4];
    const float* ln_g   = (const float*)d_in[5];
    const float* ln_b   = (const float*)d_in[6];
    const float* w_qkv  = (const float*)d_in[7];
    const float* b_qkv  = (const float*)d_in[8];
    const float* w1     = (const float*)d_in[9];
    const float* b1     = (const float*)d_in[10];
    const float* w2     = (const float*)d_in[11];
    const float* b2     = (const float*)d_in[12];
    const float* w_proj = (const float*)d_in[13];
    const float* b_proj = (const float*)d_in[14];
    float* out = (float*)d_out;

    const size_t NELEM = (size_t)NB * DIM * HW;   // 50,331,648
    // h1 lives fp32 inside d_out (dead before k_proj overwrites d_out)
    float* h1 = (float*)d_out;
    bf16* p = (bf16*)d_ws;           // LN'd window tokens (win, t, c)
    bf16* a = p + NELEM;             // attn out, then attn*gmlp (in-place)
    bf16* wqkvt = a + NELEM;         // [576][192] transposed bf16 weights
    bf16* w1t   = wqkvt + 3 * DIM * DIM;   // [768][192]
    bf16* w2t   = w1t + 4 * DIM * DIM;     // [192][768]

    // weight prep (transpose + cast); independent of data path
    k_prep<<<dim3(18, 6),  256, 0, stream>>>(w_qkv, wqkvt, DIM, 3 * DIM);
    k_prep<<<dim3(24, 6),  256, 0, stream>>>(w1, w1t, DIM, 4 * DIM);
    k_prep<<<dim3(6, 24),  256, 0, stream>>>(w2, w2t, 4 * DIM, DIM);

    k_pre1<<<dim3(1024, 3), 256, 0, stream>>>(x, w_pre1, b_pre1, h1);
    k_dwln<<<dim3(NWIN), 256, 0, stream>>>(h1, w_dw, b_dw, ln_g, ln_b, p);
    k_attn<<<dim3(NWIN), 384, 0, stream>>>(p, wqkvt, b_qkv, a);
    k_gmlp<<<dim3(NWIN / 2), 512, 0, stream>>>(p, w1t, b1, w2t, b2, a);
    k_proj<<<dim3(NWIN / 2), 256, 0, stream>>>(a, w_proj, b_proj, x, out);
}

// Round 6
// 1962.933 us; speedup vs baseline: 5.3507x; 1.0992x over previous
//
#include <hip/hip_runtime.h>
#include <hip/hip_bf16.h>
#include <math.h>

// RSWABlock: x:(16,192,128,128) fp32 -> pre1(1x1) -> dw3x3 -> LN(ch) ->
// 8x8 windows -> (attention * gMLP) -> merge -> proj(1x1) -> + x
// Round 8: k_pre1 -> bf16 MFMA GEMM (was fp32 scalar, 533us, VALUBusy 75%).
// New k_xpose transposes x NCHW fp32 -> [pix][ch] bf16 into the p region
// (dead until k_dwln), so pre1 A-fragments are contiguous-K LDS reads.

#define DIM    192
#define IMG_H  128
#define IMG_W  128
#define HW     16384        // 128*128
#define NB     16           // batch
#define NWIN   4096         // 16 batches * 16 * 16 windows
#define NHEADS 6
#define HDIM   32
#define ATT_SCALE 0.17677669529663687f  // 32^-0.5
#define LN_EPS 1e-6f

typedef __hip_bfloat16 bf16;
__device__ __forceinline__ float b2f(bf16 v) { return __bfloat162float(v); }
__device__ __forceinline__ bf16  f2b(float v) { return __float2bfloat16(v); }

typedef __bf16 bh8 __attribute__((ext_vector_type(8)));
typedef float  f32x4 __attribute__((ext_vector_type(4)));
#define MFMA16(a, b, c) __builtin_amdgcn_mfma_f32_16x16x32_bf16((a), (b), (c), 0, 0, 0)

// ---------------------------------------------------------------------------
// K0: weight prep — dst[n*K + k] = bf16(src[k*N + n])   (transpose + cast)
// ---------------------------------------------------------------------------
__global__ __launch_bounds__(256) void k_prep(
    const float* __restrict__ src, bf16* __restrict__ dst, int K, int N)
{
    __shared__ float t[32][33];
    const int tid = threadIdx.x;
    const int lx = tid & 31, ly = tid >> 5;
    const int n0 = blockIdx.x * 32, k0 = blockIdx.y * 32;
    for (int r = ly; r < 32; r += 8)
        t[r][lx] = src[(size_t)(k0 + r) * N + n0 + lx];
    __syncthreads();
    for (int r = ly; r < 32; r += 8)
        dst[(size_t)(n0 + r) * K + k0 + lx] = f2b(t[lx][r]);
}

// ---------------------------------------------------------------------------
// K0x: x NCHW fp32 -> xt[b][hw][ch] bf16 (transpose + cast per batch).
// grid (HW/32, DIM/32, NB), block 256.
// ---------------------------------------------------------------------------
__global__ __launch_bounds__(256) void k_xpose(
    const float* __restrict__ x, bf16* __restrict__ xt)
{
    __shared__ float t[32][33];
    const int tid = threadIdx.x;
    const int lx = tid & 31, ly = tid >> 5;
    const int n0 = blockIdx.x * 32;        // pixel base
    const int k0 = blockIdx.y * 32;        // channel base
    const float* src = x + (size_t)blockIdx.z * DIM * HW;
    bf16* dst = xt + (size_t)blockIdx.z * HW * DIM;
    for (int r = ly; r < 32; r += 8)
        t[r][lx] = src[(size_t)(k0 + r) * HW + n0 + lx];
    __syncthreads();
    for (int r = ly; r < 32; r += 8)
        dst[(size_t)(n0 + r) * DIM + k0 + lx] = f2b(t[lx][r]);
}

// ---------------------------------------------------------------------------
// K1: pre1 1x1 conv as bf16 MFMA GEMM. Block = 128 pixels, grid 2048.
// A = xt rows (bf16 [pix][192]), B = w_pre1 [o][c] cast to bf16 in LDS.
// Epilogue: acc -> LDS overlay -> coalesced NCHW fp32 h1 write.
// ---------------------------------------------------------------------------
__global__ __launch_bounds__(256) void k_pre1(
    const bf16* __restrict__ xt, const float* __restrict__ wp,
    const float* __restrict__ bias, float* __restrict__ h1)
{
    __shared__ __align__(16) char smem[128000];
    bf16*  mw = (bf16*)(smem);             // [128][200] 51200 B
    bf16*  wl = (bf16*)(smem + 51200);     // [192][200] 76800 B
    float* ot = (float*)(smem);            // [128][193] 98816 B, overlay

    const int tid  = threadIdx.x;
    const int wave = tid >> 6, lane = tid & 63;
    const int lid  = lane & 15, lhi = lane >> 4;
    const int g0   = blockIdx.x * 128;     // global pixel base
    const int b    = g0 >> 14;
    const int hw0  = g0 & (HW - 1);

    // stage 128 token rows from xt
    const bf16* msrc = xt + (size_t)g0 * DIM;
    for (int i = tid; i < 3072; i += 256) {
        int r = i / 24, c = (i % 24) * 8;
        *(bh8*)(mw + r * 200 + c) = *(const bh8*)(msrc + (size_t)r * 192 + c);
    }
    // stage full w_pre1 with fp32 -> bf16 cast (192x192)
    for (int i = tid; i < 9216; i += 256) {
        int r = i / 48, c = (i % 48) * 4;
        float4 v = *(const float4*)(wp + (size_t)r * 192 + c);
        bf16* d = wl + r * 200 + c;
        d[0] = f2b(v.x); d[1] = f2b(v.y); d[2] = f2b(v.z); d[3] = f2b(v.w);
    }
    __syncthreads();

    // wave computes 32 pixels x 192 o
    const int mb = wave * 32;
    f32x4 acc[2][12];
#pragma unroll
    for (int ni = 0; ni < 12; ++ni) {
        float bv = bias[ni * 16 + lid];
        f32x4 bb = {bv, bv, bv, bv};
        acc[0][ni] = bb;
        acc[1][ni] = bb;
    }
#pragma unroll
    for (int k8 = 0; k8 < 6; ++k8) {
        bh8 af0 = *(const bh8*)(mw + (mb + lid) * 200 + k8 * 32 + 8 * lhi);
        bh8 af1 = *(const bh8*)(mw + (mb + 16 + lid) * 200 + k8 * 32 + 8 * lhi);
#pragma unroll
        for (int ni = 0; ni < 12; ++ni) {
            bh8 bfr = *(const bh8*)(wl + (ni * 16 + lid) * 200 + k8 * 32 + 8 * lhi);
            acc[0][ni] = MFMA16(af0, bfr, acc[0][ni]);
            acc[1][ni] = MFMA16(af1, bfr, acc[1][ni]);
        }
    }
    __syncthreads();   // mw/wl dead; overlay ot

#pragma unroll
    for (int mi = 0; mi < 2; ++mi)
#pragma unroll
        for (int ni = 0; ni < 12; ++ni)
#pragma unroll
            for (int r = 0; r < 4; ++r)
                ot[(mb + mi * 16 + 4 * lhi + r) * 193 + ni * 16 + lid] = acc[mi][ni][r];
    __syncthreads();

    // coalesced NCHW write: 192 o x 128 contiguous pixels
    for (int i = tid; i < 24576; i += 256) {
        int o = i >> 7, pix = i & 127;
        h1[((size_t)b * DIM + o) * HW + hw0 + pix] = ot[pix * 193 + o];
    }
}

// ---------------------------------------------------------------------------
// K2: depthwise 3x3 (SAME) + bias, LayerNorm over channels, window partition.
// ---------------------------------------------------------------------------
__global__ __launch_bounds__(256) void k_dwln(
    const float* __restrict__ h1, const float* __restrict__ w_dw,
    const float* __restrict__ b_dw, const float* __restrict__ ln_g,
    const float* __restrict__ ln_b, bf16* __restrict__ p)
{
    __shared__ float tile[64 * 192];      // [pix][ch] post-conv, 48 KB
    __shared__ float patch[32 * 101];     // [ch][10x10 + pad], 12.9 KB
    const int tid = threadIdx.x;
    const int win = blockIdx.x;
    const int b = win >> 8, rem = win & 255;
    const int r0 = (rem >> 4) * 8, c0 = (rem & 15) * 8;

    for (int cc = 0; cc < 6; ++cc) {      // 6 chunks of 32 channels
        for (int i = tid; i < 3200; i += 256) {
            int ch = i / 100, pp = i % 100;
            int pr = pp / 10, pc = pp % 10;
            int gy = r0 - 1 + pr, gx = c0 - 1 + pc;
            float v = 0.f;
            if ((unsigned)gy < 128u && (unsigned)gx < 128u)
                v = h1[(((size_t)b * DIM + cc * 32 + ch) * IMG_H + gy) * IMG_W + gx];
            patch[ch * 101 + pp] = v;
        }
        __syncthreads();
        for (int i = tid; i < 2048; i += 256) {     // 64 pix * 32 ch
            int pix = i >> 5, chl = i & 31;
            int ch = cc * 32 + chl;
            int r = pix >> 3, c = pix & 7;
            float acc = b_dw[ch];
#pragma unroll
            for (int ky = 0; ky < 3; ++ky)
#pragma unroll
                for (int kx = 0; kx < 3; ++kx)
                    acc = fmaf(w_dw[ch * 9 + ky * 3 + kx],
                               patch[chl * 101 + (r + ky) * 10 + (c + kx)], acc);
            tile[pix * 192 + ch] = acc;
        }
        __syncthreads();
    }
    // LayerNorm per pixel over 192 channels: 4 threads per pixel
    const int pix = tid >> 2, sub = tid & 3;
    float s1 = 0.f, s2 = 0.f;
    for (int j = 0; j < 48; ++j) {
        float v = tile[pix * 192 + sub * 48 + j];
        s1 += v; s2 += v * v;
    }
    s1 += __shfl_xor(s1, 1); s2 += __shfl_xor(s2, 1);
    s1 += __shfl_xor(s1, 2); s2 += __shfl_xor(s2, 2);
    float mu  = s1 * (1.f / 192.f);
    float var = fmaxf(s2 * (1.f / 192.f) - mu * mu, 0.f);
    float rstd = rsqrtf(var + LN_EPS);
    bf16* pout = p + ((size_t)win * 64 + pix) * 192 + sub * 48;
    for (int j = 0; j < 48; ++j) {
        int c = sub * 48 + j;
        pout[j] = f2b((tile[pix * 192 + c] - mu) * rstd * ln_g[c] + ln_b[c]);
    }
}

// ---------------------------------------------------------------------------
// K3: per-window QKV + attention. 6 waves (384 thr), one head per wave in
// the attention phase; softmax fully in registers (shfl over lid group).
// ---------------------------------------------------------------------------
__global__ __launch_bounds__(384) void k_attn(
    const bf16* __restrict__ p, const bf16* __restrict__ wqkvt,
    const float* __restrict__ b_qkv, bf16* __restrict__ a)
{
    __shared__ __align__(16) char smem[142848];
    bf16*  qs = (bf16*)(smem);             // [64][200] 25600 B
    bf16*  ks = (bf16*)(smem + 25600);     // [64][200] 25600 B
    bf16*  vT = (bf16*)(smem + 51200);     // [192][72] 27648 B
    bf16*  ps = (bf16*)(smem + 78848);     // [64][200] 25600 B
    bf16*  wt = (bf16*)(smem + 104448);    // [96][200] 38400 B
    // head-phase overlay (ps/wt dead): 6 x [64][72] bf16 = 55296 B
    bf16*  pbase = (bf16*)(smem + 78848);

    const int tid  = threadIdx.x;
    const int wave = tid >> 6, lane = tid & 63;
    const int lid  = lane & 15, lhi = lane >> 4;
    const int win  = blockIdx.x;
    const f32x4 zero4 = {0.f, 0.f, 0.f, 0.f};

    // stage p window (64 x 192) into padded LDS
    const bf16* pwin = p + (size_t)win * 64 * 192;
    for (int i = tid; i < 1536; i += 384) {
        int r = i / 24, c = (i % 24) * 8;
        *(bh8*)(ps + r * 200 + c) = *(const bh8*)(pwin + r * 192 + c);
    }

    // ---- QKV: (64 x 192) @ (192 x 576), weight pre-transposed [576][192] ----
    const int mb  = (wave / 3) * 32;
    const int nbw = (wave % 3) * 32;
    for (int nc = 0; nc < 6; ++nc) {    // 6 chunks of 96 output cols
        for (int i = tid; i < 2304; i += 384) {   // stage weight chunk 96x192
            int r = i / 24, c = (i % 24) * 8;
            *(bh8*)(wt + r * 200 + c) =
                *(const bh8*)(wqkvt + (size_t)(nc * 96 + r) * 192 + c);
        }
        __syncthreads();

        f32x4 acc[2][2];
#pragma unroll
        for (int mi = 0; mi < 2; ++mi)
#pragma unroll
            for (int ni = 0; ni < 2; ++ni) {
                float b = b_qkv[nc * 96 + nbw + ni * 16 + lid];
                f32x4 bb = {b, b, b, b};
                acc[mi][ni] = bb;
            }
#pragma unroll
        for (int k8 = 0; k8 < 6; ++k8) {
            bh8 af[2], bfr[2];
#pragma unroll
            for (int mi = 0; mi < 2; ++mi)
                af[mi] = *(const bh8*)(ps + (mb + mi * 16 + lid) * 200 + k8 * 32 + 8 * lhi);
#pragma unroll
            for (int ni = 0; ni < 2; ++ni)
                bfr[ni] = *(const bh8*)(wt + (nbw + ni * 16 + lid) * 200 + k8 * 32 + 8 * lhi);
#pragma unroll
            for (int mi = 0; mi < 2; ++mi)
#pragma unroll
                for (int ni = 0; ni < 2; ++ni)
                    acc[mi][ni] = MFMA16(af[mi], bfr[ni], acc[mi][ni]);
        }
#pragma unroll
        for (int mi = 0; mi < 2; ++mi)
#pragma unroll
            for (int ni = 0; ni < 2; ++ni) {
                const int colg = nc * 96 + nbw + ni * 16 + lid;
#pragma unroll
                for (int r = 0; r < 4; ++r) {
                    const int t = mb + mi * 16 + 4 * lhi + r;
                    float v = acc[mi][ni][r];
                    if (colg < 192)       qs[t * 200 + colg] = f2b(v * ATT_SCALE);
                    else if (colg < 384)  ks[t * 200 + (colg - 192)] = f2b(v);
                    else                  vT[(colg - 384) * 72 + t] = f2b(v);
                }
            }
        __syncthreads();
    }

    // ---- attention: one head per wave, no barriers ----
    const int h = wave;                    // NHEADS == 6 == waves
    bf16* pw = pbase + wave * (64 * 72);   // wave-private P buffer

    f32x4 sacc[4][4];
    {
        bh8 qf[4], kf[4];
#pragma unroll
        for (int mi = 0; mi < 4; ++mi)
            qf[mi] = *(const bh8*)(qs + (mi * 16 + lid) * 200 + h * 32 + 8 * lhi);
#pragma unroll
        for (int ni = 0; ni < 4; ++ni)
            kf[ni] = *(const bh8*)(ks + (ni * 16 + lid) * 200 + h * 32 + 8 * lhi);
#pragma unroll
        for (int mi = 0; mi < 4; ++mi)
#pragma unroll
            for (int ni = 0; ni < 4; ++ni)
                sacc[mi][ni] = MFMA16(qf[mi], kf[ni], zero4);
    }

    // softmax per row, in registers
#pragma unroll
    for (int mi = 0; mi < 4; ++mi)
#pragma unroll
        for (int r = 0; r < 4; ++r) {
            float mx = fmaxf(fmaxf(sacc[mi][0][r], sacc[mi][1][r]),
                             fmaxf(sacc[mi][2][r], sacc[mi][3][r]));
            mx = fmaxf(mx, __shfl_xor(mx, 1));
            mx = fmaxf(mx, __shfl_xor(mx, 2));
            mx = fmaxf(mx, __shfl_xor(mx, 4));
            mx = fmaxf(mx, __shfl_xor(mx, 8));
            float e0 = __expf(sacc[mi][0][r] - mx);
            float e1 = __expf(sacc[mi][1][r] - mx);
            float e2 = __expf(sacc[mi][2][r] - mx);
            float e3 = __expf(sacc[mi][3][r] - mx);
            float sum = e0 + e1 + e2 + e3;
            sum += __shfl_xor(sum, 1);
            sum += __shfl_xor(sum, 2);
            sum += __shfl_xor(sum, 4);
            sum += __shfl_xor(sum, 8);
            float inv = 1.f / sum;
            sacc[mi][0][r] = e0 * inv;
            sacc[mi][1][r] = e1 * inv;
            sacc[mi][2][r] = e2 * inv;
            sacc[mi][3][r] = e3 * inv;
        }

    // P -> wave-private LDS
#pragma unroll
    for (int mi = 0; mi < 4; ++mi)
#pragma unroll
        for (int ni = 0; ni < 4; ++ni)
#pragma unroll
            for (int r = 0; r < 4; ++r)
                pw[(mi * 16 + 4 * lhi + r) * 72 + ni * 16 + lid] = f2b(sacc[mi][ni][r]);
    asm volatile("s_waitcnt lgkmcnt(0)" ::: "memory");
    __builtin_amdgcn_sched_barrier(0);

    // O = P V  (V stored transposed [ch][tok]); 16 MFMA
    f32x4 oacc[4][2];
#pragma unroll
    for (int mi = 0; mi < 4; ++mi)
#pragma unroll
        for (int nb2 = 0; nb2 < 2; ++nb2) oacc[mi][nb2] = zero4;
#pragma unroll
    for (int kk = 0; kk < 2; ++kk) {
        bh8 pf[4];
#pragma unroll
        for (int mi = 0; mi < 4; ++mi)
            pf[mi] = *(const bh8*)(pw + (mi * 16 + lid) * 72 + kk * 32 + 8 * lhi);
#pragma unroll
        for (int nb2 = 0; nb2 < 2; ++nb2) {
            bh8 vf = *(const bh8*)(vT + (h * 32 + nb2 * 16 + lid) * 72 + kk * 32 + 8 * lhi);
#pragma unroll
            for (int mi = 0; mi < 4; ++mi)
                oacc[mi][nb2] = MFMA16(pf[mi], vf, oacc[mi][nb2]);
        }
    }
#pragma unroll
    for (int mi = 0; mi < 4; ++mi)
#pragma unroll
        for (int nb2 = 0; nb2 < 2; ++nb2)
#pragma unroll
            for (int r = 0; r < 4; ++r) {
                const int t = mi * 16 + 4 * lhi + r;
                a[((size_t)win * 64 + t) * 192 + h * 32 + nb2 * 16 + lid] =
                    f2b(oacc[mi][nb2][r]);
            }
}

// ---------------------------------------------------------------------------
// K4: gMLP (gelu(p@w1+b1)@w2+b2) via MFMA, multiply with attn out in-place.
// 2 windows per block (128 tokens), 8 waves (512 thr), grid NWIN/2 = 2048.
// ---------------------------------------------------------------------------
__global__ __launch_bounds__(512) void k_gmlp(
    const bf16* __restrict__ p, const bf16* __restrict__ w1t,
    const float* __restrict__ b1, const bf16* __restrict__ w2t,
    const float* __restrict__ b2, bf16* __restrict__ a)
{
    __shared__ __align__(16) char smem[122880];
    bf16* ps  = (bf16*)(smem);             // [128][200] 51200 B
    bf16* w1c = (bf16*)(smem + 51200);     // [64][200]  25600 B
    bf16* w2c = (bf16*)(smem + 76800);     // [192][72]  27648 B
    bf16* hb  = (bf16*)(smem + 104448);    // [128][72]  18432 B

    const int tid  = threadIdx.x;
    const int wave = tid >> 6, lane = tid & 63;
    const int lid  = lane & 15, lhi = lane >> 4;
    const int win0 = blockIdx.x * 2;       // two contiguous windows

    const bf16* pwin = p + (size_t)win0 * 64 * 192;
    for (int i = tid; i < 3072; i += 512) {
        int r = i / 24, c = (i % 24) * 8;
        *(bh8*)(ps + r * 200 + c) = *(const bh8*)(pwin + (size_t)r * 192 + c);
    }

    f32x4 acc2[12];
#pragma unroll
    for (int ni = 0; ni < 12; ++ni) {
        float b = b2[ni * 16 + lid];
        f32x4 bb = {b, b, b, b};
        acc2[ni] = bb;
    }
    const int mb = (wave >> 1) * 32, nb = (wave & 1) * 32;

    for (int hc = 0; hc < 12; ++hc) {
        for (int i = tid; i < 1536; i += 512) {   // w1 chunk [64 hid][192 k]
            int r = i / 24, c = (i % 24) * 8;
            *(bh8*)(w1c + r * 200 + c) =
                *(const bh8*)(w1t + (size_t)(hc * 64 + r) * 192 + c);
        }
        for (int i = tid; i < 1536; i += 512) {   // w2 chunk [192 out][64 k]
            int r = i / 8, c = (i % 8) * 8;
            *(bh8*)(w2c + r * 72 + c) =
                *(const bh8*)(w2t + (size_t)r * 768 + hc * 64 + c);
        }
        __syncthreads();

        // GEMM1: hidden chunk (128 x 64), wave tile 32 x 32
        f32x4 acc1[2][2];
#pragma unroll
        for (int mi = 0; mi < 2; ++mi)
#pragma unroll
            for (int ni = 0; ni < 2; ++ni) {
                float b = b1[hc * 64 + nb + ni * 16 + lid];
                f32x4 bb = {b, b, b, b};
                acc1[mi][ni] = bb;
            }
#pragma unroll
        for (int k8 = 0; k8 < 6; ++k8) {
            bh8 af0 = *(const bh8*)(ps + (mb + lid) * 200 + k8 * 32 + 8 * lhi);
            bh8 af1 = *(const bh8*)(ps + (mb + 16 + lid) * 200 + k8 * 32 + 8 * lhi);
            bh8 bf0 = *(const bh8*)(w1c + (nb + lid) * 200 + k8 * 32 + 8 * lhi);
            bh8 bf1 = *(const bh8*)(w1c + (nb + 16 + lid) * 200 + k8 * 32 + 8 * lhi);
            acc1[0][0] = MFMA16(af0, bf0, acc1[0][0]);
            acc1[0][1] = MFMA16(af0, bf1, acc1[0][1]);
            acc1[1][0] = MFMA16(af1, bf0, acc1[1][0]);
            acc1[1][1] = MFMA16(af1, bf1, acc1[1][1]);
        }
        // exact GELU -> hb (bf16)
#pragma unroll
        for (int mi = 0; mi < 2; ++mi)
#pragma unroll
            for (int ni = 0; ni < 2; ++ni)
#pragma unroll
                for (int r = 0; r < 4; ++r) {
                    int row = mb + mi * 16 + 4 * lhi + r;
                    int col = nb + ni * 16 + lid;
                    float xv = acc1[mi][ni][r];
                    hb[row * 72 + col] =
                        f2b(0.5f * xv * (1.f + erff(xv * 0.70710678118654752f)));
                }
        __syncthreads();

        // GEMM2: acc2 (16 rows x 192 cols per wave) += hb @ w2chunk
#pragma unroll
        for (int kk = 0; kk < 2; ++kk) {
            bh8 hf = *(const bh8*)(hb + (wave * 16 + lid) * 72 + kk * 32 + 8 * lhi);
#pragma unroll
            for (int ni = 0; ni < 12; ++ni) {
                bh8 wf = *(const bh8*)(w2c + (ni * 16 + lid) * 72 + kk * 32 + 8 * lhi);
                acc2[ni] = MFMA16(hf, wf, acc2[ni]);
            }
        }
        __syncthreads();
    }

    // epilogue: out = attn * gmlp, in-place on a (rows 0..127 of 2 windows)
    bf16* awin = a + (size_t)win0 * 64 * 192;
#pragma unroll
    for (int ni = 0; ni < 12; ++ni)
#pragma unroll
        for (int r = 0; r < 4; ++r) {
            int t = wave * 16 + 4 * lhi + r;
            int col = ni * 16 + lid;
            size_t idx = (size_t)t * 192 + col;
            awin[idx] = f2b(acc2[ni][r] * b2f(awin[idx]));
        }
}

// ---------------------------------------------------------------------------
// K5: proj 1x1 + bias + residual via bf16 MFMA. Block = 2 adjacent windows
// (128 tokens), grid NWIN/2 = 2048, 4 waves.
// ---------------------------------------------------------------------------
__global__ __launch_bounds__(256) void k_proj(
    const bf16* __restrict__ m, const float* __restrict__ wp,
    const float* __restrict__ b_proj, const float* __restrict__ x,
    float* __restrict__ out)
{
    __shared__ __align__(16) char smem[128000];
    bf16*  mw = (bf16*)(smem);             // [128][200] 51200 B
    bf16*  wl = (bf16*)(smem + 51200);     // [192][200] 76800 B
    float* ot = (float*)(smem);            // [128][193] 98816 B, overlay

    const int tid  = threadIdx.x;
    const int wave = tid >> 6, lane = tid & 63;
    const int lid  = lane & 15, lhi = lane >> 4;
    const int bp   = blockIdx.x;           // [0, 2048)
    const int b    = bp >> 7, rem = bp & 127;
    const int wr   = rem >> 3, wcp = rem & 7;
    const int win0 = b * 256 + wr * 16 + wcp * 2;   // win1 = win0+1 contiguous
    const int r0   = wr * 8, c0 = wcp * 16;

    // stage 128 tokens (2 windows, contiguous in m)
    const bf16* msrc = m + (size_t)win0 * 64 * 192;
    for (int i = tid; i < 3072; i += 256) {
        int r = i / 24, c = (i % 24) * 8;
        *(bh8*)(mw + r * 200 + c) = *(const bh8*)(msrc + (size_t)r * 192 + c);
    }
    // stage full w_proj with fp32 -> bf16 cast (192x192, float4 loads)
    for (int i = tid; i < 9216; i += 256) {
        int r = i / 48, c = (i % 48) * 4;
        float4 v = *(const float4*)(wp + (size_t)r * 192 + c);
        bf16* d = wl + r * 200 + c;
        d[0] = f2b(v.x); d[1] = f2b(v.y); d[2] = f2b(v.z); d[3] = f2b(v.w);
    }
    __syncthreads();

    // wave computes 32 tokens x 192 o
    const int mb = wave * 32;
    f32x4 acc[2][12];
#pragma unroll
    for (int ni = 0; ni < 12; ++ni) {
        float bv = b_proj[ni * 16 + lid];
        f32x4 bb = {bv, bv, bv, bv};
        acc[0][ni] = bb;
        acc[1][ni] = bb;
    }
#pragma unroll
    for (int k8 = 0; k8 < 6; ++k8) {
        bh8 af0 = *(const bh8*)(mw + (mb + lid) * 200 + k8 * 32 + 8 * lhi);
        bh8 af1 = *(const bh8*)(mw + (mb + 16 + lid) * 200 + k8 * 32 + 8 * lhi);
#pragma unroll
        for (int ni = 0; ni < 12; ++ni) {
            bh8 bfr = *(const bh8*)(wl + (ni * 16 + lid) * 200 + k8 * 32 + 8 * lhi);
            acc[0][ni] = MFMA16(af0, bfr, acc[0][ni]);
            acc[1][ni] = MFMA16(af1, bfr, acc[1][ni]);
        }
    }
    __syncthreads();   // mw/wl dead; overlay ot

#pragma unroll
    for (int mi = 0; mi < 2; ++mi)
#pragma unroll
        for (int ni = 0; ni < 12; ++ni)
#pragma unroll
            for (int r = 0; r < 4; ++r)
                ot[(mb + mi * 16 + 4 * lhi + r) * 193 + ni * 16 + lid] = acc[mi][ni][r];
    __syncthreads();

    // coalesced NCHW write: region = 8 rows x 16 cols (two windows), 192 o
    for (int i = tid; i < 24576; i += 256) {
        int o = i >> 7, pix = i & 127;
        int r = pix >> 4, cc = pix & 15;
        int trow = ((cc >> 3) << 6) + r * 8 + (cc & 7);   // token row in ot
        size_t idx = (((size_t)b * DIM + o) * IMG_H + r0 + r) * IMG_W + c0 + cc;
        out[idx] = ot[trow * 193 + o] + x[idx];           // + residual
    }
}

// ---------------------------------------------------------------------------
extern "C" void kernel_launch(void* const* d_in, const int* in_sizes, int n_in,
                              void* d_out, int out_size, void* d_ws, size_t ws_size,
                              hipStream_t stream)
{
    const float* x      = (const float*)d_in[0];
    const float* w_pre1 = (const float*)d_in[1];
    const float* b_pre1 = (const float*)d_in[2];
    const float* w_dw   = (const float*)d_in[3];
    const float* b_dw   = (const float*)d_in[4];
    const float* ln_g   = (const float*)d_in[5];
    const float* ln_b   = (const float*)d_in[6];
    const float* w_qkv  = (const float*)d_in[7];
    const float* b_qkv  = (const float*)d_in[8];
    const float* w1     = (const float*)d_in[9];
    const float* b1     = (const float*)d_in[10];
    const float* w2     = (const float*)d_in[11];
    const float* b2     = (const float*)d_in[12];
    const float* w_proj = (const float*)d_in[13];
    const float* b_proj = (const float*)d_in[14];
    float* out = (float*)d_out;

    const size_t NELEM = (size_t)NB * DIM * HW;   // 50,331,648
    // h1 lives fp32 inside d_out (dead before k_proj overwrites d_out)
    float* h1 = (float*)d_out;
    bf16* p = (bf16*)d_ws;           // xt first, then LN'd window tokens
    bf16* a = p + NELEM;             // attn out, then attn*gmlp (in-place)
    bf16* wqkvt = a + NELEM;         // [576][192] transposed bf16 weights
    bf16* w1t   = wqkvt + 3 * DIM * DIM;   // [768][192]
    bf16* w2t   = w1t + 4 * DIM * DIM;     // [192][768]

    // weight prep (transpose + cast); independent of data path
    k_prep<<<dim3(18, 6),  256, 0, stream>>>(w_qkv, wqkvt, DIM, 3 * DIM);
    k_prep<<<dim3(24, 6),  256, 0, stream>>>(w1, w1t, DIM, 4 * DIM);
    k_prep<<<dim3(6, 24),  256, 0, stream>>>(w2, w2t, 4 * DIM, DIM);

    // xt (bf16 [b][hw][ch]) lives in the p region, dead until k_dwln
    bf16* xt = p;
    k_xpose<<<dim3(HW / 32, DIM / 32, NB), 256, 0, stream>>>(x, xt);
    k_pre1<<<dim3(2048), 256, 0, stream>>>(xt, w_pre1, b_pre1, h1);
    k_dwln<<<dim3(NWIN), 256, 0, stream>>>(h1, w_dw, b_dw, ln_g, ln_b, p);
    k_attn<<<dim3(NWIN), 384, 0, stream>>>(p, wqkvt, b_qkv, a);
    k_gmlp<<<dim3(NWIN / 2), 512, 0, stream>>>(p, w1t, b1, w2t, b2, a);
    k_proj<<<dim3(NWIN / 2), 256, 0, stream>>>(a, w_proj, b_proj, x, out);
}